// Round 5
// baseline (149.284 us; speedup 1.0000x reference)
//
#include <hip/hip_runtime.h>
#include <hip/hip_bf16.h>

typedef __attribute__((ext_vector_type(4))) float f32x4;
typedef __attribute__((ext_vector_type(8))) short bf16x8;

static constexpr int B   = 2;
static constexpr int N   = 2048;
static constexpr int F   = 64;
static constexpr int H   = 4;
static constexpr int HID = 128;
static constexpr int BN  = B * N;
static constexpr size_t LOG_SZ = (size_t)B * N * N * 3;

__device__ __forceinline__ float sigmoidf_(float x) { return 1.0f / (1.0f + __expf(-x)); }
__device__ __forceinline__ float tanhf_(float x) {
  float e = __expf(2.0f * x);
  return 1.0f - 2.0f / (e + 1.0f);      // inf-safe
}
// RNE bf16 split: v = hi + lo with ~2^-17 relative error
__device__ __forceinline__ void split_bf16(float v, short& hi, short& lo) {
  unsigned u = __float_as_uint(v);
  unsigned hr = (u + 0x7FFFu + ((u >> 16) & 1u)) >> 16;
  hi = (short)hr;
  float hv = __uint_as_float(hr << 16);
  float res = v - hv;
  unsigned u2 = __float_as_uint(res);
  lo = (short)((u2 + 0x7FFFu + ((u2 >> 16) & 1u)) >> 16);
}

// ------------- K0: transpose + bf16x2-split all 12 weight matrices -------------
struct PrepArgs {
  const float* src[12];
  short* hi[12];
  short* lo[12];
  int K[12];
};
__global__ __launch_bounds__(256) void k_prep_w(PrepArgs pa) {
  const int m  = blockIdx.y;
  const int K  = pa.K[m];
  const int kt = blockIdx.x >> 2;
  const int ct = blockIdx.x & 3;
  if (kt * 32 >= K) return;
  const int t  = threadIdx.x;
  const int tx = t & 31, ty = t >> 5;
  __shared__ float tl[32][33];
  const float* src = pa.src[m];
  #pragma unroll
  for (int p = 0; p < 4; ++p) {
    const int r = ty + p * 8;
    tl[r][tx] = src[(size_t)(kt * 32 + r) * HID + ct * 32 + tx];
  }
  __syncthreads();
  short* ph = pa.hi[m];
  short* pl = pa.lo[m];
  #pragma unroll
  for (int p = 0; p < 4; ++p) {
    const int cl = ty + p * 8;
    float v = tl[tx][cl];
    short hi, lo; split_bf16(v, hi, lo);
    const size_t o = (size_t)(ct * 32 + cl) * K + kt * 32 + tx;
    ph[o] = hi; pl[o] = lo;
  }
}

// ------------- K1: hfeat = x @ gat_kernel ; s_self, s_neigh ; h -> bf16x2 -------------
__global__ __launch_bounds__(128) void k_feat(
    const float* __restrict__ x, const float* __restrict__ gk,
    const float* __restrict__ asel, const float* __restrict__ anei,
    float* __restrict__ hfeat, float* __restrict__ sself, float* __restrict__ sneigh,
    const float* __restrict__ h0, const float* __restrict__ h1, const float* __restrict__ h2,
    short* __restrict__ hh0, short* __restrict__ hl0,
    short* __restrict__ hh1, short* __restrict__ hl1,
    short* __restrict__ hh2, short* __restrict__ hl2) {
  const int bn = blockIdx.x;
  const int t  = threadIdx.x;
  __shared__ float xs[F];
  if (t < F) xs[t] = x[(size_t)bn * F + t];
  const size_t o = (size_t)bn * HID + t;
  { short hi, lo; split_bf16(h0[o], hi, lo); hh0[o] = hi; hl0[o] = lo; }
  { short hi, lo; split_bf16(h1[o], hi, lo); hh1[o] = hi; hl1[o] = lo; }
  { short hi, lo; split_bf16(h2[o], hi, lo); hh2[o] = hi; hl2[o] = lo; }
  __syncthreads();
  float acc = 0.f;
  #pragma unroll 8
  for (int f = 0; f < F; ++f) acc += xs[f] * gk[f * HID + t];
  hfeat[o] = acc;
  float ps = acc * asel[t];
  float pn = acc * anei[t];
  #pragma unroll
  for (int d = 16; d >= 1; d >>= 1) {
    ps += __shfl_xor(ps, d, 32);
    pn += __shfl_xor(pn, d, 32);
  }
  if ((t & 31) == 0) {
    sself [bn * H + (t >> 5)] = ps;
    sneigh[bn * H + (t >> 5)] = pn;
  }
}

// ------------- K2: sparse GAT attention — one wave per row -------------
__global__ __launch_bounds__(256) void k_attn(
    const float* __restrict__ a, const float* __restrict__ hfeat,
    const float* __restrict__ sself, const float* __restrict__ sneigh,
    const float* __restrict__ bias,
    short* __restrict__ conv_hi, short* __restrict__ conv_lo) {
  const int wv   = threadIdx.x >> 6;
  const int lane = threadIdx.x & 63;
  const int bi   = blockIdx.x * 4 + wv;
  const int bbase = bi & ~(N - 1);
  __shared__ int   nbr[4][256];
  __shared__ float wts[4][256][4];
  int*   nb       = nbr[wv];
  float (*wt)[4]  = wts[wv];

  const float si0 = sself[bi * H + 0];
  const float si1 = sself[bi * H + 1];
  const float si2 = sself[bi * H + 2];
  const float si3 = sself[bi * H + 3];
  float den0 = 0.f, den1 = 0.f, den2 = 0.f, den3 = 0.f;
  float acc0 = 0.f, acc1 = 0.f;
  const unsigned long long lmlt = ((unsigned long long)1 << lane) - 1ull;
  const float* arow = a + (size_t)bi * N;
  const float* hb   = hfeat + (size_t)bbase * HID;
  const float* snb  = sneigh + (size_t)bbase * H;
  const int h0 = lane >> 5;
  int num = 0;

  auto flush = [&]() {
    asm volatile("s_waitcnt lgkmcnt(0)" ::: "memory");
    for (int n = lane; n < num; n += 64) {
      const int j = nb[n];
      f32x4 sn = *(const f32x4*)&snb[(size_t)j * H];
      float s0 = si0 + sn[0]; s0 = (s0 > 0.f) ? s0 : 0.2f * s0;
      float s1 = si1 + sn[1]; s1 = (s1 > 0.f) ? s1 : 0.2f * s1;
      float s2 = si2 + sn[2]; s2 = (s2 > 0.f) ? s2 : 0.2f * s2;
      float s3 = si3 + sn[3]; s3 = (s3 > 0.f) ? s3 : 0.2f * s3;
      float w0 = __expf(s0), w1 = __expf(s1), w2 = __expf(s2), w3 = __expf(s3);
      wt[n][0] = w0; wt[n][1] = w1; wt[n][2] = w2; wt[n][3] = w3;
      den0 += w0; den1 += w1; den2 += w2; den3 += w3;
    }
    asm volatile("s_waitcnt lgkmcnt(0)" ::: "memory");
    #pragma unroll 4
    for (int n = 0; n < num; ++n) {
      const int j  = nb[n];
      const float wA = wt[n][h0];
      const float wB = wt[n][h0 + 2];
      const float* hr = hb + (size_t)j * HID;
      acc0 += wA * hr[lane];
      acc1 += wB * hr[lane + 64];
    }
    asm volatile("s_waitcnt lgkmcnt(0)" ::: "memory");
    num = 0;
  };

  for (int jb = 0; jb < N; jb += 256) {
    f32x4 av = *(const f32x4*)&arow[jb + lane * 4];
    #pragma unroll
    for (int e = 0; e < 4; ++e) {
      const unsigned long long m = __ballot(av[e] > 0.5f);
      if (av[e] > 0.5f) {
        const int pos = num + __popcll(m & lmlt);
        nb[pos] = jb + lane * 4 + e;
      }
      num += __popcll(m);
      if (num > 192) flush();
    }
  }
  if (num > 0) flush();

  #pragma unroll
  for (int d = 32; d >= 1; d >>= 1) {
    den0 += __shfl_xor(den0, d, 64);
    den1 += __shfl_xor(den1, d, 64);
    den2 += __shfl_xor(den2, d, 64);
    den3 += __shfl_xor(den3, d, 64);
  }
  const float dA = h0 ? den1 : den0;
  const float dB = h0 ? den3 : den2;
  const float v0 = acc0 / dA + bias[lane];
  const float v1 = acc1 / dB + bias[64 + lane];
  { short hi, lo; split_bf16(v0, hi, lo);
    conv_hi[(size_t)bi * HID + lane] = hi; conv_lo[(size_t)bi * HID + lane] = lo; }
  { short hi, lo; split_bf16(v1, hi, lo);
    conv_hi[(size_t)bi * HID + 64 + lane] = hi; conv_lo[(size_t)bi * HID + 64 + lane] = lo; }
}

// ------------- shared arg pack -------------
struct GArgs {
  const short* chi; const short* clo;
  const float* h[3];
  const short* hhi[3]; const short* hlo[3];
  const float* bu[3]; const float* br[3]; const float* bc[3];
  const short* WuH[3]; const short* WuL[3];
  const short* WrH[3]; const short* WrL[3];
  const short* WcH[3]; const short* WcL[3];
  const short* RtH[3]; const short* RtL[3];
  float* u_ws[3];
  short* rhh[3]; short* rhl[3];
  float* hout[3]; __hip_bfloat16* hb[3]; __hip_bfloat16* gb[3];
};

// ------------- K3: u,r gates — one gate per block, 16x32 per wave -------------
// grid (BN/64, 4 colgrps, 2 gates * 3 cells); 256 thr = 4 row-stacked waves
__global__ __launch_bounds__(256, 4) void k_ur(GArgs ga) {
  const int w = threadIdx.x >> 6, l = threadIdx.x & 63;
  const int bx = blockIdx.x;
  const int cg = blockIdx.y;
  const int gate = blockIdx.z & 1, cell = blockIdx.z >> 1;
  const int R0 = bx * 64 + w * 16;
  const int cb = cg * 32;
  const int lr = l & 15, lg = l >> 4, kb = lg * 8;
  const short* Ah_c = ga.chi;       const short* Al_c = ga.clo;
  const short* Ah_h = ga.hhi[cell]; const short* Al_h = ga.hlo[cell];
  const short* BH = gate ? ga.WrH[cell] : ga.WuH[cell];
  const short* BL = gate ? ga.WrL[cell] : ga.WuL[cell];
  const size_t abase = (size_t)(R0 + lr) * HID + kb;
  f32x4 acc[2] = {};
  #pragma unroll
  for (int ks = 0; ks < 8; ++ks) {
    const int k2 = (ks + bx) & 7;          // per-block K-stagger
    const short* Ah = (k2 < 4) ? Ah_c : Ah_h;
    const short* Al = (k2 < 4) ? Al_c : Al_h;
    bf16x8 ah = *(const bf16x8*)&Ah[abase + (size_t)(k2 & 3) * 32];
    bf16x8 al = *(const bf16x8*)&Al[abase + (size_t)(k2 & 3) * 32];
    #pragma unroll
    for (int cf = 0; cf < 2; ++cf) {
      const size_t wo = (size_t)(cb + cf * 16 + lr) * 256 + k2 * 32 + kb;
      bf16x8 bh = *(const bf16x8*)&BH[wo];
      bf16x8 bl = *(const bf16x8*)&BL[wo];
      acc[cf] = __builtin_amdgcn_mfma_f32_16x16x32_bf16(ah, bh, acc[cf], 0, 0, 0);
      acc[cf] = __builtin_amdgcn_mfma_f32_16x16x32_bf16(ah, bl, acc[cf], 0, 0, 0);
      acc[cf] = __builtin_amdgcn_mfma_f32_16x16x32_bf16(al, bh, acc[cf], 0, 0, 0);
    }
  }
  const float* bias = gate ? ga.br[cell] : ga.bu[cell];
  if (gate == 0) {
    float* u = ga.u_ws[cell];
    #pragma unroll
    for (int cf = 0; cf < 2; ++cf) {
      const int col = cb + cf * 16 + lr;
      #pragma unroll
      for (int q = 0; q < 4; ++q) {
        const int row = R0 + lg * 4 + q;
        u[(size_t)row * HID + col] = sigmoidf_(acc[cf][q] + bias[row & (N - 1)]);
      }
    }
  } else {
    const float* hsrc = ga.h[cell];
    short* rhh = ga.rhh[cell]; short* rhl = ga.rhl[cell];
    #pragma unroll
    for (int cf = 0; cf < 2; ++cf) {
      const int col = cb + cf * 16 + lr;
      #pragma unroll
      for (int q = 0; q < 4; ++q) {
        const int row = R0 + lg * 4 + q;
        const float rv = sigmoidf_(acc[cf][q] + bias[row & (N - 1)]);
        const float rh = rv * hsrc[(size_t)row * HID + col];
        short hi, lo; split_bf16(rh, hi, lo);
        rhh[(size_t)row * HID + col] = hi;
        rhl[(size_t)row * HID + col] = lo;
      }
    }
  }
}

// ------------- K4: c gate + h' + g = h' @ R  (fused via LDS) -------------
// grid (BN/16, 3 cells); 512 thr = 8 col-waves of 16 cols; 16 rows per block
__global__ __launch_bounds__(512, 4) void k_cg(GArgs ga) {
  const int w = threadIdx.x >> 6, l = threadIdx.x & 63;
  const int bx = blockIdx.x, cell = blockIdx.y;
  const int R0 = bx * 16;
  const int cb = w * 16;
  const int lr = l & 15, lg = l >> 4, kb = lg * 8;
  __shared__ float hp_lds[16][132];
  const size_t abase = (size_t)(R0 + lr) * HID + kb;
  const short* WcH = ga.WcH[cell]; const short* WcL = ga.WcL[cell];
  f32x4 acc = {};
  #pragma unroll
  for (int ks = 0; ks < 8; ++ks) {
    const int k2 = (ks + bx) & 7;
    const short* Ah = (k2 < 4) ? ga.chi : ga.rhh[cell];
    const short* Al = (k2 < 4) ? ga.clo : ga.rhl[cell];
    bf16x8 ah = *(const bf16x8*)&Ah[abase + (size_t)(k2 & 3) * 32];
    bf16x8 al = *(const bf16x8*)&Al[abase + (size_t)(k2 & 3) * 32];
    const size_t wo = (size_t)(cb + lr) * 256 + k2 * 32 + kb;
    bf16x8 bh = *(const bf16x8*)&WcH[wo];
    bf16x8 bl = *(const bf16x8*)&WcL[wo];
    acc = __builtin_amdgcn_mfma_f32_16x16x32_bf16(ah, bh, acc, 0, 0, 0);
    acc = __builtin_amdgcn_mfma_f32_16x16x32_bf16(ah, bl, acc, 0, 0, 0);
    acc = __builtin_amdgcn_mfma_f32_16x16x32_bf16(al, bh, acc, 0, 0, 0);
  }
  // c epilogue: h' = u*h + (1-u)*tanh(c)
  {
    const float* bc = ga.bc[cell];
    const float* uw = ga.u_ws[cell];
    const float* hsrc = ga.h[cell];
    float* hout = ga.hout[cell];
    __hip_bfloat16* hbo = ga.hb[cell];
    const int col = cb + lr;
    #pragma unroll
    for (int q = 0; q < 4; ++q) {
      const int row = R0 + lg * 4 + q;
      const float cv = tanhf_(acc[q] + bc[row & (N - 1)]);
      const float uv = uw[(size_t)row * HID + col];
      const float hv = hsrc[(size_t)row * HID + col];
      const float o = uv * hv + (1.f - uv) * cv;
      hout[(size_t)row * HID + col] = o;
      hbo[(size_t)row * HID + col] = __float2bfloat16(o);
      hp_lds[lg * 4 + q][col] = o;
    }
  }
  __syncthreads();
  // g phase: g = h' @ R, K=128, A from LDS
  const short* RtH = ga.RtH[cell]; const short* RtL = ga.RtL[cell];
  f32x4 ag = {};
  #pragma unroll
  for (int ks = 0; ks < 4; ++ks) {
    const float* p = &hp_lds[lr][ks * 32 + kb];
    f32x4 f0 = *(const f32x4*)p;
    f32x4 f1 = *(const f32x4*)(p + 4);
    bf16x8 ah, al;
    #pragma unroll
    for (int e = 0; e < 4; ++e) { short hi, lo; split_bf16(f0[e], hi, lo); ah[e] = hi; al[e] = lo; }
    #pragma unroll
    for (int e = 0; e < 4; ++e) { short hi, lo; split_bf16(f1[e], hi, lo); ah[4 + e] = hi; al[4 + e] = lo; }
    const size_t wo = (size_t)(cb + lr) * 128 + ks * 32 + kb;
    bf16x8 bh = *(const bf16x8*)&RtH[wo];
    bf16x8 bl = *(const bf16x8*)&RtL[wo];
    ag = __builtin_amdgcn_mfma_f32_16x16x32_bf16(ah, bh, ag, 0, 0, 0);
    ag = __builtin_amdgcn_mfma_f32_16x16x32_bf16(ah, bl, ag, 0, 0, 0);
    ag = __builtin_amdgcn_mfma_f32_16x16x32_bf16(al, bh, ag, 0, 0, 0);
  }
  __hip_bfloat16* gbo = ga.gb[cell];
  const int col = cb + lr;
  #pragma unroll
  for (int q = 0; q < 4; ++q) {
    const int row = R0 + lg * 4 + q;
    gbo[(size_t)row * HID + col] = __float2bfloat16(ag[q]);
  }
}

// ------------- K5: logits[b,i,j,k] = g_k[b,i,:] . h_k[b,j,:]  (bf16 MFMA, NT) -------------
__global__ __launch_bounds__(256) void k_bilinear(
    const __hip_bfloat16* __restrict__ g0, const __hip_bfloat16* __restrict__ g1,
    const __hip_bfloat16* __restrict__ g2, const __hip_bfloat16* __restrict__ h0,
    const __hip_bfloat16* __restrict__ h1, const __hip_bfloat16* __restrict__ h2,
    float* __restrict__ out) {
  const int ti = blockIdx.x, tj = blockIdx.y, b = blockIdx.z;
  const int t = threadIdx.x;
  const int w = t >> 6, l = t & 63;
  const int wi = w >> 1, wj = w & 1;
  const int i_base = ti * 64 + wi * 32;
  const int j_base = tj * 64 + wj * 32;
  const __hip_bfloat16* gbs[3] = {g0, g1, g2};
  const __hip_bfloat16* hbs[3] = {h0, h1, h2};
  const int lr = l & 15;
  const int kb = (l >> 4) * 8;
  f32x4 acc[3][2][2] = {};
  for (int k0 = 0; k0 < HID; k0 += 32) {
    bf16x8 af[3][2], bfr[3][2];
    #pragma unroll
    for (int d = 0; d < 3; ++d) {
      #pragma unroll
      for (int m = 0; m < 2; ++m) {
        af[d][m]  = *(const bf16x8*)&gbs[d][(size_t)(b * N + i_base + m * 16 + lr) * HID + k0 + kb];
        bfr[d][m] = *(const bf16x8*)&hbs[d][(size_t)(b * N + j_base + m * 16 + lr) * HID + k0 + kb];
      }
    }
    #pragma unroll
    for (int d = 0; d < 3; ++d)
      #pragma unroll
      for (int mi = 0; mi < 2; ++mi)
        #pragma unroll
        for (int mj = 0; mj < 2; ++mj)
          acc[d][mi][mj] = __builtin_amdgcn_mfma_f32_16x16x32_bf16(
              af[d][mi], bfr[d][mj], acc[d][mi][mj], 0, 0, 0);
  }
  const int orow = (l >> 4) * 4;
  const int col  = l & 15;
  #pragma unroll
  for (int mi = 0; mi < 2; ++mi)
    #pragma unroll
    for (int mj = 0; mj < 2; ++mj)
      #pragma unroll
      for (int r = 0; r < 4; ++r) {
        const int row = i_base + mi * 16 + orow + r;
        const int cc  = j_base + mj * 16 + col;
        float* p = &out[(((size_t)(b * N + row)) * N + cc) * 3];
        p[0] = acc[0][mi][mj][r];
        p[1] = acc[1][mi][mj][r];
        p[2] = acc[2][mi][mj][r];
      }
}

extern "C" void kernel_launch(void* const* d_in, const int* in_sizes, int n_in,
                              void* d_out, int out_size, void* d_ws, size_t ws_size,
                              hipStream_t stream) {
  (void)in_sizes; (void)n_in; (void)out_size; (void)ws_size;
  const float* x    = (const float*)d_in[0];
  const float* a    = (const float*)d_in[1];
  const float* gk   = (const float*)d_in[5];
  const float* asel = (const float*)d_in[6];
  const float* anei = (const float*)d_in[7];
  const float* bias = (const float*)d_in[8];

  float* ws      = (float*)d_ws;
  float* hfeat   = ws;                                    // BN*HID f32
  float* sself   = hfeat + (size_t)BN * HID;
  float* sneigh  = sself + (size_t)BN * H;
  float* u_ws0   = sneigh + (size_t)BN * H;               // 3 * BN*HID f32
  short* sp      = (short*)(u_ws0 + 3 * (size_t)BN * HID);
  auto alloc_s = [&](size_t n) { short* p = sp; sp += n; return p; };

  short* conv_hi = alloc_s((size_t)BN * HID);
  short* conv_lo = alloc_s((size_t)BN * HID);
  short* h_hi[3]; short* h_lo[3];
  for (int c = 0; c < 3; ++c) { h_hi[c] = alloc_s((size_t)BN * HID); h_lo[c] = alloc_s((size_t)BN * HID); }
  short* rh_hi[3]; short* rh_lo[3];
  for (int c = 0; c < 3; ++c) { rh_hi[c] = alloc_s((size_t)BN * HID); rh_lo[c] = alloc_s((size_t)BN * HID); }
  __hip_bfloat16* hbb[3]; __hip_bfloat16* gbb[3];
  for (int c = 0; c < 3; ++c) {
    hbb[c] = (__hip_bfloat16*)alloc_s((size_t)BN * HID);
    gbb[c] = (__hip_bfloat16*)alloc_s((size_t)BN * HID);
  }

  float* out = (float*)d_out;

  PrepArgs pa;
  GArgs ga;
  ga.chi = conv_hi; ga.clo = conv_lo;
  ga.h[0] = (const float*)d_in[2];
  ga.h[1] = (const float*)d_in[3];
  ga.h[2] = (const float*)d_in[4];
  for (int c = 0; c < 3; ++c) {
    const int base = 9 + c * 6;
    ga.hhi[c] = h_hi[c]; ga.hlo[c] = h_lo[c];
    ga.bu[c] = (const float*)d_in[base + 1];
    ga.br[c] = (const float*)d_in[base + 3];
    ga.bc[c] = (const float*)d_in[base + 5];
    short* wu_h = alloc_s(256 * 128); short* wu_l = alloc_s(256 * 128);
    short* wr_h = alloc_s(256 * 128); short* wr_l = alloc_s(256 * 128);
    short* wc_h = alloc_s(256 * 128); short* wc_l = alloc_s(256 * 128);
    short* rt_h = alloc_s(128 * 128); short* rt_l = alloc_s(128 * 128);
    const int pb = c * 4;
    pa.src[pb + 0] = (const float*)d_in[base + 0]; pa.hi[pb + 0] = wu_h; pa.lo[pb + 0] = wu_l; pa.K[pb + 0] = 256;
    pa.src[pb + 1] = (const float*)d_in[base + 2]; pa.hi[pb + 1] = wr_h; pa.lo[pb + 1] = wr_l; pa.K[pb + 1] = 256;
    pa.src[pb + 2] = (const float*)d_in[base + 4]; pa.hi[pb + 2] = wc_h; pa.lo[pb + 2] = wc_l; pa.K[pb + 2] = 256;
    pa.src[pb + 3] = (const float*)d_in[27 + c];   pa.hi[pb + 3] = rt_h; pa.lo[pb + 3] = rt_l; pa.K[pb + 3] = 128;
    ga.WuH[c] = wu_h; ga.WuL[c] = wu_l;
    ga.WrH[c] = wr_h; ga.WrL[c] = wr_l;
    ga.WcH[c] = wc_h; ga.WcL[c] = wc_l;
    ga.RtH[c] = rt_h; ga.RtL[c] = rt_l;
    ga.u_ws[c] = u_ws0 + (size_t)c * BN * HID;
    ga.rhh[c] = rh_hi[c]; ga.rhl[c] = rh_lo[c];
    ga.hout[c] = out + LOG_SZ + (size_t)c * BN * HID;
    ga.hb[c] = hbb[c];
    ga.gb[c] = gbb[c];
  }

  k_prep_w<<<dim3(32, 12), 256, 0, stream>>>(pa);
  k_feat<<<BN, 128, 0, stream>>>(x, gk, asel, anei, hfeat, sself, sneigh,
                                 ga.h[0], ga.h[1], ga.h[2],
                                 h_hi[0], h_lo[0], h_hi[1], h_lo[1], h_hi[2], h_lo[2]);
  k_attn<<<BN / 4, 256, 0, stream>>>(a, hfeat, sself, sneigh, bias, conv_hi, conv_lo);
  k_ur<<<dim3(BN / 64, 4, 6), 256, 0, stream>>>(ga);
  k_cg<<<dim3(BN / 16, 3), 512, 0, stream>>>(ga);
  dim3 g2(N / 64, N / 64, B);
  k_bilinear<<<g2, 256, 0, stream>>>(gbb[0], gbb[1], gbb[2],
                                     hbb[0], hbb[1], hbb[2], out);
}

// Round 6
// 122.492 us; speedup vs baseline: 1.2187x; 1.2187x over previous
//
#include <hip/hip_runtime.h>
#include <hip/hip_bf16.h>

typedef __attribute__((ext_vector_type(4))) float f32x4;
typedef __attribute__((ext_vector_type(8))) short bf16x8;

static constexpr int B   = 2;
static constexpr int N   = 2048;
static constexpr int F   = 64;
static constexpr int H   = 4;
static constexpr int HID = 128;
static constexpr int BN  = B * N;
static constexpr size_t LOG_SZ = (size_t)B * N * N * 3;

__device__ __forceinline__ float sigmoidf_(float x) { return 1.0f / (1.0f + __expf(-x)); }
__device__ __forceinline__ float tanhf_(float x) {
  float e = __expf(2.0f * x);
  return 1.0f - 2.0f / (e + 1.0f);      // inf-safe
}
// RNE bf16 split: v = hi + lo with ~2^-17 relative error
__device__ __forceinline__ void split_bf16(float v, short& hi, short& lo) {
  unsigned u = __float_as_uint(v);
  unsigned hr = (u + 0x7FFFu + ((u >> 16) & 1u)) >> 16;
  hi = (short)hr;
  float hv = __uint_as_float(hr << 16);
  float res = v - hv;
  unsigned u2 = __float_as_uint(res);
  lo = (short)((u2 + 0x7FFFu + ((u2 >> 16) & 1u)) >> 16);
}

// ------------- K0: weights -> bf16x2 split in MFMA-FRAGMENT order -------------
// dst layout per matrix: frag (cf 0..7, ks 0..nks-1): [((cf*nks+ks)*64+lane)*8+e]
// holds W[k = ks*32+(lane>>4)*8+e][col = cf*16+(lane&15)], W row-major [K][128].
struct PrepArgs {
  const float* src[12];
  short* hi[12];
  short* lo[12];
  int nks[12];               // 8 for W (K=256), 4 for R (K=128)
};
__global__ __launch_bounds__(256) void k_prep_w(PrepArgs pa) {
  const int m  = blockIdx.y;
  const int cf = blockIdx.x;           // 0..7
  const int nks = pa.nks[m];
  const int wv = threadIdx.x >> 6, lane = threadIdx.x & 63;
  const float* src = pa.src[m];
  short* ph = pa.hi[m];
  short* pl = pa.lo[m];
  const int col = cf * 16 + (lane & 15);
  const int krow = (lane >> 4) * 8;
  for (int ks = wv; ks < nks; ks += 4) {
    bf16x8 vh, vl;
    #pragma unroll
    for (int e = 0; e < 8; ++e) {
      const int k = ks * 32 + krow + e;
      short hi, lo; split_bf16(src[(size_t)k * HID + col], hi, lo);
      vh[e] = hi; vl[e] = lo;
    }
    const size_t o = (((size_t)cf * nks + ks) * 64 + lane) * 8;
    *(bf16x8*)&ph[o] = vh;
    *(bf16x8*)&pl[o] = vl;
  }
}

// ------------- K1: hfeat = x @ gat_kernel ; s_self, s_neigh ; h -> bf16x2 -------------
__global__ __launch_bounds__(128) void k_feat(
    const float* __restrict__ x, const float* __restrict__ gk,
    const float* __restrict__ asel, const float* __restrict__ anei,
    float* __restrict__ hfeat, float* __restrict__ sself, float* __restrict__ sneigh,
    const float* __restrict__ h0, const float* __restrict__ h1, const float* __restrict__ h2,
    short* __restrict__ hh0, short* __restrict__ hl0,
    short* __restrict__ hh1, short* __restrict__ hl1,
    short* __restrict__ hh2, short* __restrict__ hl2) {
  const int bn = blockIdx.x;
  const int t  = threadIdx.x;
  __shared__ float xs[F];
  if (t < F) xs[t] = x[(size_t)bn * F + t];
  const size_t o = (size_t)bn * HID + t;
  { short hi, lo; split_bf16(h0[o], hi, lo); hh0[o] = hi; hl0[o] = lo; }
  { short hi, lo; split_bf16(h1[o], hi, lo); hh1[o] = hi; hl1[o] = lo; }
  { short hi, lo; split_bf16(h2[o], hi, lo); hh2[o] = hi; hl2[o] = lo; }
  __syncthreads();
  float acc = 0.f;
  #pragma unroll 8
  for (int f = 0; f < F; ++f) acc += xs[f] * gk[f * HID + t];
  hfeat[o] = acc;
  float ps = acc * asel[t];
  float pn = acc * anei[t];
  #pragma unroll
  for (int d = 16; d >= 1; d >>= 1) {
    ps += __shfl_xor(ps, d, 32);
    pn += __shfl_xor(pn, d, 32);
  }
  if ((t & 31) == 0) {
    sself [bn * H + (t >> 5)] = ps;
    sneigh[bn * H + (t >> 5)] = pn;
  }
}

// ------------- K2: sparse GAT attention — one wave per row -------------
__global__ __launch_bounds__(256) void k_attn(
    const float* __restrict__ a, const float* __restrict__ hfeat,
    const float* __restrict__ sself, const float* __restrict__ sneigh,
    const float* __restrict__ bias,
    short* __restrict__ conv_hi, short* __restrict__ conv_lo) {
  const int wv   = threadIdx.x >> 6;
  const int lane = threadIdx.x & 63;
  const int bi   = blockIdx.x * 4 + wv;
  const int bbase = bi & ~(N - 1);
  __shared__ int   nbr[4][256];
  __shared__ float wts[4][256][4];
  int*   nb       = nbr[wv];
  float (*wt)[4]  = wts[wv];

  const float si0 = sself[bi * H + 0];
  const float si1 = sself[bi * H + 1];
  const float si2 = sself[bi * H + 2];
  const float si3 = sself[bi * H + 3];
  float den0 = 0.f, den1 = 0.f, den2 = 0.f, den3 = 0.f;
  float acc0 = 0.f, acc1 = 0.f;
  const unsigned long long lmlt = ((unsigned long long)1 << lane) - 1ull;
  const float* arow = a + (size_t)bi * N;
  const float* hb   = hfeat + (size_t)bbase * HID;
  const float* snb  = sneigh + (size_t)bbase * H;
  const int h0 = lane >> 5;
  int num = 0;

  auto flush = [&]() {
    asm volatile("s_waitcnt lgkmcnt(0)" ::: "memory");
    for (int n = lane; n < num; n += 64) {
      const int j = nb[n];
      f32x4 sn = *(const f32x4*)&snb[(size_t)j * H];
      float s0 = si0 + sn[0]; s0 = (s0 > 0.f) ? s0 : 0.2f * s0;
      float s1 = si1 + sn[1]; s1 = (s1 > 0.f) ? s1 : 0.2f * s1;
      float s2 = si2 + sn[2]; s2 = (s2 > 0.f) ? s2 : 0.2f * s2;
      float s3 = si3 + sn[3]; s3 = (s3 > 0.f) ? s3 : 0.2f * s3;
      float w0 = __expf(s0), w1 = __expf(s1), w2 = __expf(s2), w3 = __expf(s3);
      wt[n][0] = w0; wt[n][1] = w1; wt[n][2] = w2; wt[n][3] = w3;
      den0 += w0; den1 += w1; den2 += w2; den3 += w3;
    }
    asm volatile("s_waitcnt lgkmcnt(0)" ::: "memory");
    #pragma unroll 4
    for (int n = 0; n < num; ++n) {
      const int j  = nb[n];
      const float wA = wt[n][h0];
      const float wB = wt[n][h0 + 2];
      const float* hr = hb + (size_t)j * HID;
      acc0 += wA * hr[lane];
      acc1 += wB * hr[lane + 64];
    }
    asm volatile("s_waitcnt lgkmcnt(0)" ::: "memory");
    num = 0;
  };

  for (int jb = 0; jb < N; jb += 256) {
    f32x4 av = *(const f32x4*)&arow[jb + lane * 4];
    #pragma unroll
    for (int e = 0; e < 4; ++e) {
      const unsigned long long m = __ballot(av[e] > 0.5f);
      if (av[e] > 0.5f) {
        const int pos = num + __popcll(m & lmlt);
        nb[pos] = jb + lane * 4 + e;
      }
      num += __popcll(m);
      if (num > 192) flush();
    }
  }
  if (num > 0) flush();

  #pragma unroll
  for (int d = 32; d >= 1; d >>= 1) {
    den0 += __shfl_xor(den0, d, 64);
    den1 += __shfl_xor(den1, d, 64);
    den2 += __shfl_xor(den2, d, 64);
    den3 += __shfl_xor(den3, d, 64);
  }
  const float dA = h0 ? den1 : den0;
  const float dB = h0 ? den3 : den2;
  const float v0 = acc0 / dA + bias[lane];
  const float v1 = acc1 / dB + bias[64 + lane];
  { short hi, lo; split_bf16(v0, hi, lo);
    conv_hi[(size_t)bi * HID + lane] = hi; conv_lo[(size_t)bi * HID + lane] = lo; }
  { short hi, lo; split_bf16(v1, hi, lo);
    conv_hi[(size_t)bi * HID + 64 + lane] = hi; conv_lo[(size_t)bi * HID + 64 + lane] = lo; }
}

// ------------- shared arg pack -------------
struct GArgs {
  const short* chi; const short* clo;
  const float* h[3];
  const short* hhi[3]; const short* hlo[3];
  const float* bu[3]; const float* br[3]; const float* bc[3];
  const short* WuH[3]; const short* WuL[3];
  const short* WrH[3]; const short* WrL[3];
  const short* WcH[3]; const short* WcL[3];
  const short* RtH[3]; const short* RtL[3];
  float* u_ws[3];
  short* rhh[3]; short* rhl[3];
  short* hph[3]; short* hpl[3];
  float* hout[3]; __hip_bfloat16* hb[3]; __hip_bfloat16* gb[3];
};

// ------------- K3: u+r gates. 64 rows x 32 cols/block; weights LDS-resident -------------
// grid (BN/64, 4 colgroups, 3 cells), 256 thr = 4 waves (16 rows each).
__global__ __launch_bounds__(256, 2) void k_ur(GArgs ga) {
  const int wv = threadIdx.x >> 6, lane = threadIdx.x & 63;
  const int bx = blockIdx.x, cg = blockIdx.y, cell = blockIdx.z;
  const int lr = lane & 15, lg = lane >> 4, kb = lg * 8;
  const int R0 = bx * 64 + wv * 16;
  __shared__ short wlds[4][16][64][8];   // combo {uh,ul,rh,rl} x frag x lane x 8 = 64KB

  // A-fragments: [conv | h], all 16 preloaded
  bf16x8 a_h[8], a_l[8];
  {
    const size_t ab = (size_t)(R0 + lr) * HID + kb;
    const short* hhi = ga.hhi[cell]; const short* hlo = ga.hlo[cell];
    #pragma unroll
    for (int ks = 0; ks < 4; ++ks) {
      a_h[ks]     = *(const bf16x8*)&ga.chi[ab + ks * 32];
      a_l[ks]     = *(const bf16x8*)&ga.clo[ab + ks * 32];
      a_h[4 + ks] = *(const bf16x8*)&hhi[ab + ks * 32];
      a_l[4 + ks] = *(const bf16x8*)&hlo[ab + ks * 32];
    }
  }
  // stage weights: wave wv stages combo wv (16 frags x 1KB)
  {
    const short* srcs[4] = { ga.WuH[cell], ga.WuL[cell], ga.WrH[cell], ga.WrL[cell] };
    const short* sp = srcs[wv];
    #pragma unroll
    for (int f = 0; f < 16; ++f) {
      const size_t go = (((size_t)(cg * 2 + (f >> 3)) * 8 + (f & 7)) * 64 + lane) * 8;
      *(bf16x8*)&wlds[wv][f][lane][0] = *(const bf16x8*)&sp[go];
    }
  }
  __syncthreads();

  f32x4 au[2] = {}, ar[2] = {};
  #pragma unroll
  for (int ks = 0; ks < 8; ++ks) {
    const bf16x8 ah = a_h[ks], al = a_l[ks];
    #pragma unroll
    for (int cfl = 0; cfl < 2; ++cfl) {
      const int f = cfl * 8 + ks;
      bf16x8 buh = *(const bf16x8*)&wlds[0][f][lane][0];
      bf16x8 bul = *(const bf16x8*)&wlds[1][f][lane][0];
      bf16x8 brh = *(const bf16x8*)&wlds[2][f][lane][0];
      bf16x8 brl = *(const bf16x8*)&wlds[3][f][lane][0];
      au[cfl] = __builtin_amdgcn_mfma_f32_16x16x32_bf16(ah, buh, au[cfl], 0, 0, 0);
      au[cfl] = __builtin_amdgcn_mfma_f32_16x16x32_bf16(ah, bul, au[cfl], 0, 0, 0);
      au[cfl] = __builtin_amdgcn_mfma_f32_16x16x32_bf16(al, buh, au[cfl], 0, 0, 0);
      ar[cfl] = __builtin_amdgcn_mfma_f32_16x16x32_bf16(ah, brh, ar[cfl], 0, 0, 0);
      ar[cfl] = __builtin_amdgcn_mfma_f32_16x16x32_bf16(ah, brl, ar[cfl], 0, 0, 0);
      ar[cfl] = __builtin_amdgcn_mfma_f32_16x16x32_bf16(al, brh, ar[cfl], 0, 0, 0);
    }
  }
  const float* bu = ga.bu[cell]; const float* br = ga.br[cell];
  const float* hsrc = ga.h[cell];
  float* uws = ga.u_ws[cell];
  short* rhh = ga.rhh[cell]; short* rhl = ga.rhl[cell];
  #pragma unroll
  for (int cfl = 0; cfl < 2; ++cfl) {
    const int col = cg * 32 + cfl * 16 + lr;
    #pragma unroll
    for (int q = 0; q < 4; ++q) {
      const int row = R0 + lg * 4 + q;
      const int n = row & (N - 1);
      uws[(size_t)row * HID + col] = sigmoidf_(au[cfl][q] + bu[n]);
      const float rv = sigmoidf_(ar[cfl][q] + br[n]);
      const float rhv = rv * hsrc[(size_t)row * HID + col];
      short hi, lo; split_bf16(rhv, hi, lo);
      rhh[(size_t)row * HID + col] = hi;
      rhl[(size_t)row * HID + col] = lo;
    }
  }
}

// ------------- K4: c gate + h'. 64 rows x 32 cols/block -------------
__global__ __launch_bounds__(256, 2) void k_c(GArgs ga) {
  const int wv = threadIdx.x >> 6, lane = threadIdx.x & 63;
  const int bx = blockIdx.x, cg = blockIdx.y, cell = blockIdx.z;
  const int lr = lane & 15, lg = lane >> 4, kb = lg * 8;
  const int R0 = bx * 64 + wv * 16;
  __shared__ short wlds[2][16][64][8];   // {ch, cl} x 16 frags = 32KB

  bf16x8 a_h[8], a_l[8];
  {
    const size_t ab = (size_t)(R0 + lr) * HID + kb;
    const short* rhh = ga.rhh[cell]; const short* rhl = ga.rhl[cell];
    #pragma unroll
    for (int ks = 0; ks < 4; ++ks) {
      a_h[ks]     = *(const bf16x8*)&ga.chi[ab + ks * 32];
      a_l[ks]     = *(const bf16x8*)&ga.clo[ab + ks * 32];
      a_h[4 + ks] = *(const bf16x8*)&rhh[ab + ks * 32];
      a_l[4 + ks] = *(const bf16x8*)&rhl[ab + ks * 32];
    }
  }
  {
    const short* sp = (wv >> 1) ? ga.WcL[cell] : ga.WcH[cell];
    #pragma unroll
    for (int i = 0; i < 8; ++i) {
      const int f = (wv & 1) * 8 + i;
      const size_t go = (((size_t)(cg * 2 + (f >> 3)) * 8 + (f & 7)) * 64 + lane) * 8;
      *(bf16x8*)&wlds[wv >> 1][f][lane][0] = *(const bf16x8*)&sp[go];
    }
  }
  __syncthreads();

  f32x4 ac[2] = {};
  #pragma unroll
  for (int ks = 0; ks < 8; ++ks) {
    const bf16x8 ah = a_h[ks], al = a_l[ks];
    #pragma unroll
    for (int cfl = 0; cfl < 2; ++cfl) {
      const int f = cfl * 8 + ks;
      bf16x8 bh = *(const bf16x8*)&wlds[0][f][lane][0];
      bf16x8 bl = *(const bf16x8*)&wlds[1][f][lane][0];
      ac[cfl] = __builtin_amdgcn_mfma_f32_16x16x32_bf16(ah, bh, ac[cfl], 0, 0, 0);
      ac[cfl] = __builtin_amdgcn_mfma_f32_16x16x32_bf16(ah, bl, ac[cfl], 0, 0, 0);
      ac[cfl] = __builtin_amdgcn_mfma_f32_16x16x32_bf16(al, bh, ac[cfl], 0, 0, 0);
    }
  }
  const float* bc = ga.bc[cell];
  const float* uw = ga.u_ws[cell];
  const float* hsrc = ga.h[cell];
  float* hout = ga.hout[cell];
  __hip_bfloat16* hbo = ga.hb[cell];
  short* hph = ga.hph[cell]; short* hpl = ga.hpl[cell];
  #pragma unroll
  for (int cfl = 0; cfl < 2; ++cfl) {
    const int col = cg * 32 + cfl * 16 + lr;
    #pragma unroll
    for (int q = 0; q < 4; ++q) {
      const int row = R0 + lg * 4 + q;
      const int n = row & (N - 1);
      const float cv = tanhf_(ac[cfl][q] + bc[n]);
      const float uv = uw[(size_t)row * HID + col];
      const float hv = hsrc[(size_t)row * HID + col];
      const float o = uv * hv + (1.f - uv) * cv;
      hout[(size_t)row * HID + col] = o;
      hbo[(size_t)row * HID + col] = __float2bfloat16(o);
      short hi, lo; split_bf16(o, hi, lo);
      hph[(size_t)row * HID + col] = hi;
      hpl[(size_t)row * HID + col] = lo;
    }
  }
}

// ------------- K5: g = h' @ R. 64 rows x 32 cols/block, K=128 -------------
__global__ __launch_bounds__(256, 2) void k_g(GArgs ga) {
  const int wv = threadIdx.x >> 6, lane = threadIdx.x & 63;
  const int bx = blockIdx.x, cg = blockIdx.y, cell = blockIdx.z;
  const int lr = lane & 15, lg = lane >> 4, kb = lg * 8;
  const int R0 = bx * 64 + wv * 16;
  __shared__ short wlds[2][8][64][8];    // {Rh, Rl} x 8 frags = 16KB

  bf16x8 a_h[4], a_l[4];
  {
    const size_t ab = (size_t)(R0 + lr) * HID + kb;
    const short* hph = ga.hph[cell]; const short* hpl = ga.hpl[cell];
    #pragma unroll
    for (int ks = 0; ks < 4; ++ks) {
      a_h[ks] = *(const bf16x8*)&hph[ab + ks * 32];
      a_l[ks] = *(const bf16x8*)&hpl[ab + ks * 32];
    }
  }
  {
    #pragma unroll
    for (int i = 0; i < 4; ++i) {
      const int fg = wv * 4 + i;             // 0..15
      const int combo = fg >> 3, f = fg & 7; // f = cfl*4+ks
      const short* sp = combo ? ga.RtL[cell] : ga.RtH[cell];
      const size_t go = (((size_t)(cg * 2 + (f >> 2)) * 4 + (f & 3)) * 64 + lane) * 8;
      *(bf16x8*)&wlds[combo][f][lane][0] = *(const bf16x8*)&sp[go];
    }
  }
  __syncthreads();

  f32x4 ag[2] = {};
  #pragma unroll
  for (int ks = 0; ks < 4; ++ks) {
    const bf16x8 ah = a_h[ks], al = a_l[ks];
    #pragma unroll
    for (int cfl = 0; cfl < 2; ++cfl) {
      const int f = cfl * 4 + ks;
      bf16x8 bh = *(const bf16x8*)&wlds[0][f][lane][0];
      bf16x8 bl = *(const bf16x8*)&wlds[1][f][lane][0];
      ag[cfl] = __builtin_amdgcn_mfma_f32_16x16x32_bf16(ah, bh, ag[cfl], 0, 0, 0);
      ag[cfl] = __builtin_amdgcn_mfma_f32_16x16x32_bf16(ah, bl, ag[cfl], 0, 0, 0);
      ag[cfl] = __builtin_amdgcn_mfma_f32_16x16x32_bf16(al, bh, ag[cfl], 0, 0, 0);
    }
  }
  __hip_bfloat16* gbo = ga.gb[cell];
  #pragma unroll
  for (int cfl = 0; cfl < 2; ++cfl) {
    const int col = cg * 32 + cfl * 16 + lr;
    #pragma unroll
    for (int q = 0; q < 4; ++q) {
      const int row = R0 + lg * 4 + q;
      gbo[(size_t)row * HID + col] = __float2bfloat16(ag[cfl][q]);
    }
  }
}

// ------------- K6: logits[b,i,j,k] = g_k[b,i,:] . h_k[b,j,:]  (bf16 MFMA, NT) -------------
__global__ __launch_bounds__(256) void k_bilinear(
    const __hip_bfloat16* __restrict__ g0, const __hip_bfloat16* __restrict__ g1,
    const __hip_bfloat16* __restrict__ g2, const __hip_bfloat16* __restrict__ h0,
    const __hip_bfloat16* __restrict__ h1, const __hip_bfloat16* __restrict__ h2,
    float* __restrict__ out) {
  const int ti = blockIdx.x, tj = blockIdx.y, b = blockIdx.z;
  const int t = threadIdx.x;
  const int w = t >> 6, l = t & 63;
  const int wi = w >> 1, wj = w & 1;
  const int i_base = ti * 64 + wi * 32;
  const int j_base = tj * 64 + wj * 32;
  const __hip_bfloat16* gbs[3] = {g0, g1, g2};
  const __hip_bfloat16* hbs[3] = {h0, h1, h2};
  const int lr = l & 15;
  const int kb = (l >> 4) * 8;
  f32x4 acc[3][2][2] = {};
  for (int k0 = 0; k0 < HID; k0 += 32) {
    bf16x8 af[3][2], bfr[3][2];
    #pragma unroll
    for (int d = 0; d < 3; ++d) {
      #pragma unroll
      for (int m = 0; m < 2; ++m) {
        af[d][m]  = *(const bf16x8*)&gbs[d][(size_t)(b * N + i_base + m * 16 + lr) * HID + k0 + kb];
        bfr[d][m] = *(const bf16x8*)&hbs[d][(size_t)(b * N + j_base + m * 16 + lr) * HID + k0 + kb];
      }
    }
    #pragma unroll
    for (int d = 0; d < 3; ++d)
      #pragma unroll
      for (int mi = 0; mi < 2; ++mi)
        #pragma unroll
        for (int mj = 0; mj < 2; ++mj)
          acc[d][mi][mj] = __builtin_amdgcn_mfma_f32_16x16x32_bf16(
              af[d][mi], bfr[d][mj], acc[d][mi][mj], 0, 0, 0);
  }
  const int orow = (l >> 4) * 4;
  const int col  = l & 15;
  #pragma unroll
  for (int mi = 0; mi < 2; ++mi)
    #pragma unroll
    for (int mj = 0; mj < 2; ++mj)
      #pragma unroll
      for (int r = 0; r < 4; ++r) {
        const int row = i_base + mi * 16 + orow + r;
        const int cc  = j_base + mj * 16 + col;
        float* p = &out[(((size_t)(b * N + row)) * N + cc) * 3];
        p[0] = acc[0][mi][mj][r];
        p[1] = acc[1][mi][mj][r];
        p[2] = acc[2][mi][mj][r];
      }
}

extern "C" void kernel_launch(void* const* d_in, const int* in_sizes, int n_in,
                              void* d_out, int out_size, void* d_ws, size_t ws_size,
                              hipStream_t stream) {
  (void)in_sizes; (void)n_in; (void)out_size; (void)ws_size;
  const float* x    = (const float*)d_in[0];
  const float* a    = (const float*)d_in[1];
  const float* gk   = (const float*)d_in[5];
  const float* asel = (const float*)d_in[6];
  const float* anei = (const float*)d_in[7];
  const float* bias = (const float*)d_in[8];

  float* ws      = (float*)d_ws;
  float* hfeat   = ws;                                    // BN*HID f32
  float* sself   = hfeat + (size_t)BN * HID;
  float* sneigh  = sself + (size_t)BN * H;
  float* u_ws0   = sneigh + (size_t)BN * H;               // 3 * BN*HID f32
  short* sp      = (short*)(u_ws0 + 3 * (size_t)BN * HID);
  auto alloc_s = [&](size_t n) { short* p = sp; sp += n; return p; };

  short* conv_hi = alloc_s((size_t)BN * HID);
  short* conv_lo = alloc_s((size_t)BN * HID);
  short* h_hi[3]; short* h_lo[3];
  for (int c = 0; c < 3; ++c) { h_hi[c] = alloc_s((size_t)BN * HID); h_lo[c] = alloc_s((size_t)BN * HID); }
  short* rh_hi[3]; short* rh_lo[3];
  for (int c = 0; c < 3; ++c) { rh_hi[c] = alloc_s((size_t)BN * HID); rh_lo[c] = alloc_s((size_t)BN * HID); }
  short* hp_hi[3]; short* hp_lo[3];
  for (int c = 0; c < 3; ++c) { hp_hi[c] = alloc_s((size_t)BN * HID); hp_lo[c] = alloc_s((size_t)BN * HID); }
  __hip_bfloat16* hbb[3]; __hip_bfloat16* gbb[3];
  for (int c = 0; c < 3; ++c) {
    hbb[c] = (__hip_bfloat16*)alloc_s((size_t)BN * HID);
    gbb[c] = (__hip_bfloat16*)alloc_s((size_t)BN * HID);
  }

  float* out = (float*)d_out;

  PrepArgs pa;
  GArgs ga;
  ga.chi = conv_hi; ga.clo = conv_lo;
  ga.h[0] = (const float*)d_in[2];
  ga.h[1] = (const float*)d_in[3];
  ga.h[2] = (const float*)d_in[4];
  for (int c = 0; c < 3; ++c) {
    const int base = 9 + c * 6;
    ga.hhi[c] = h_hi[c]; ga.hlo[c] = h_lo[c];
    ga.bu[c] = (const float*)d_in[base + 1];
    ga.br[c] = (const float*)d_in[base + 3];
    ga.bc[c] = (const float*)d_in[base + 5];
    short* wu_h = alloc_s(256 * 128); short* wu_l = alloc_s(256 * 128);
    short* wr_h = alloc_s(256 * 128); short* wr_l = alloc_s(256 * 128);
    short* wc_h = alloc_s(256 * 128); short* wc_l = alloc_s(256 * 128);
    short* rt_h = alloc_s(128 * 128); short* rt_l = alloc_s(128 * 128);
    const int pb = c * 4;
    pa.src[pb + 0] = (const float*)d_in[base + 0]; pa.hi[pb + 0] = wu_h; pa.lo[pb + 0] = wu_l; pa.nks[pb + 0] = 8;
    pa.src[pb + 1] = (const float*)d_in[base + 2]; pa.hi[pb + 1] = wr_h; pa.lo[pb + 1] = wr_l; pa.nks[pb + 1] = 8;
    pa.src[pb + 2] = (const float*)d_in[base + 4]; pa.hi[pb + 2] = wc_h; pa.lo[pb + 2] = wc_l; pa.nks[pb + 2] = 8;
    pa.src[pb + 3] = (const float*)d_in[27 + c];   pa.hi[pb + 3] = rt_h; pa.lo[pb + 3] = rt_l; pa.nks[pb + 3] = 4;
    ga.WuH[c] = wu_h; ga.WuL[c] = wu_l;
    ga.WrH[c] = wr_h; ga.WrL[c] = wr_l;
    ga.WcH[c] = wc_h; ga.WcL[c] = wc_l;
    ga.RtH[c] = rt_h; ga.RtL[c] = rt_l;
    ga.u_ws[c] = u_ws0 + (size_t)c * BN * HID;
    ga.rhh[c] = rh_hi[c]; ga.rhl[c] = rh_lo[c];
    ga.hph[c] = hp_hi[c]; ga.hpl[c] = hp_lo[c];
    ga.hout[c] = out + LOG_SZ + (size_t)c * BN * HID;
    ga.hb[c] = hbb[c];
    ga.gb[c] = gbb[c];
  }

  k_prep_w<<<dim3(8, 12), 256, 0, stream>>>(pa);
  k_feat<<<BN, 128, 0, stream>>>(x, gk, asel, anei, hfeat, sself, sneigh,
                                 ga.h[0], ga.h[1], ga.h[2],
                                 h_hi[0], h_lo[0], h_hi[1], h_lo[1], h_hi[2], h_lo[2]);
  k_attn<<<BN / 4, 256, 0, stream>>>(a, hfeat, sself, sneigh, bias, conv_hi, conv_lo);
  dim3 gg(BN / 64, 4, 3);
  k_ur<<<gg, 256, 0, stream>>>(ga);
  k_c<<<gg, 256, 0, stream>>>(ga);
  k_g<<<gg, 256, 0, stream>>>(ga);
  dim3 g2(N / 64, N / 64, B);
  k_bilinear<<<g2, 256, 0, stream>>>(gbb[0], gbb[1], gbb[2],
                                     hbb[0], hbb[1], hbb[2], out);
}

// Round 7
// 116.327 us; speedup vs baseline: 1.2833x; 1.0530x over previous
//
#include <hip/hip_runtime.h>
#include <hip/hip_bf16.h>

typedef __attribute__((ext_vector_type(4))) float f32x4;
typedef __attribute__((ext_vector_type(8))) short bf16x8;

static constexpr int B   = 2;
static constexpr int N   = 2048;
static constexpr int F   = 64;
static constexpr int H   = 4;
static constexpr int HID = 128;
static constexpr int BN  = B * N;
static constexpr size_t LOG_SZ = (size_t)B * N * N * 3;

__device__ __forceinline__ float sigmoidf_(float x) { return 1.0f / (1.0f + __expf(-x)); }
__device__ __forceinline__ float tanhf_(float x) {
  float e = __expf(2.0f * x);
  return 1.0f - 2.0f / (e + 1.0f);      // inf-safe
}
// RNE bf16 split: v = hi + lo with ~2^-17 relative error
__device__ __forceinline__ void split_bf16(float v, short& hi, short& lo) {
  unsigned u = __float_as_uint(v);
  unsigned hr = (u + 0x7FFFu + ((u >> 16) & 1u)) >> 16;
  hi = (short)hr;
  float hv = __uint_as_float(hr << 16);
  float res = v - hv;
  unsigned u2 = __float_as_uint(res);
  lo = (short)((u2 + 0x7FFFu + ((u2 >> 16) & 1u)) >> 16);
}

__device__ __forceinline__ void stage16(const short* gp, short* lp) {
  __builtin_amdgcn_global_load_lds(
      (const __attribute__((address_space(1))) void*)gp,
      (__attribute__((address_space(3))) void*)lp, 16, 0, 0);
}

// ------------- K1: merged prep (weights->frag-order bf16x2) + feat + h-split ---
// blocks [0, BN/2): feat 2 rows each. blocks [BN/2, BN/2+96): weight prep.
struct PreArgs {
  const float* x; const float* gk; const float* asel; const float* anei;
  float* hfeat; float* sself; float* sneigh;
  const float* h[3];
  short* hh[3]; short* hl[3];
  const float* src[12];
  short* whi[12]; short* wlo[12];
  int nks[12];               // 8 for W (K=256), 4 for R (K=128)
};
__global__ __launch_bounds__(256) void k_pre(PreArgs pa) {
  const int bid = blockIdx.x;
  if (bid < BN / 2) {
    const int t = threadIdx.x;
    const int r = t >> 7, tt = t & 127;
    const int bn = bid * 2 + r;
    __shared__ float xs[2][F];
    if (tt < F) xs[r][tt] = pa.x[(size_t)bn * F + tt];
    const size_t o = (size_t)bn * HID + tt;
    { short hi, lo; split_bf16(pa.h[0][o], hi, lo); pa.hh[0][o] = hi; pa.hl[0][o] = lo; }
    { short hi, lo; split_bf16(pa.h[1][o], hi, lo); pa.hh[1][o] = hi; pa.hl[1][o] = lo; }
    { short hi, lo; split_bf16(pa.h[2][o], hi, lo); pa.hh[2][o] = hi; pa.hl[2][o] = lo; }
    __syncthreads();
    float acc = 0.f;
    #pragma unroll 8
    for (int f = 0; f < F; ++f) acc += xs[r][f] * pa.gk[f * HID + tt];
    pa.hfeat[o] = acc;
    float ps = acc * pa.asel[tt];
    float pn = acc * pa.anei[tt];
    #pragma unroll
    for (int d = 16; d >= 1; d >>= 1) {
      ps += __shfl_xor(ps, d, 32);
      pn += __shfl_xor(pn, d, 32);
    }
    if ((tt & 31) == 0) {
      pa.sself [bn * H + (tt >> 5)] = ps;
      pa.sneigh[bn * H + (tt >> 5)] = pn;
    }
  } else {
    const int pb = bid - BN / 2;         // 0..95
    const int m = pb >> 3, cf = pb & 7;
    const int nksv = pa.nks[m];
    const int wv = threadIdx.x >> 6, lane = threadIdx.x & 63;
    const float* src = pa.src[m];
    short* ph = pa.whi[m];
    short* pl = pa.wlo[m];
    const int col = cf * 16 + (lane & 15);
    const int krow = (lane >> 4) * 8;
    for (int ks = wv; ks < nksv; ks += 4) {
      bf16x8 vh, vl;
      #pragma unroll
      for (int e = 0; e < 8; ++e) {
        const int k = ks * 32 + krow + e;
        short hi, lo; split_bf16(src[(size_t)k * HID + col], hi, lo);
        vh[e] = hi; vl[e] = lo;
      }
      const size_t o = (((size_t)cf * nksv + ks) * 64 + lane) * 8;
      *(bf16x8*)&ph[o] = vh;
      *(bf16x8*)&pl[o] = vl;
    }
  }
}

// ------------- K2: sparse GAT attention — one wave per row -------------
__global__ __launch_bounds__(256) void k_attn(
    const float* __restrict__ a, const float* __restrict__ hfeat,
    const float* __restrict__ sself, const float* __restrict__ sneigh,
    const float* __restrict__ bias,
    short* __restrict__ conv_hi, short* __restrict__ conv_lo) {
  const int wv   = threadIdx.x >> 6;
  const int lane = threadIdx.x & 63;
  const int bi   = blockIdx.x * 4 + wv;
  const int bbase = bi & ~(N - 1);
  __shared__ int   nbr[4][256];
  __shared__ float wts[4][256][4];
  int*   nb       = nbr[wv];
  float (*wt)[4]  = wts[wv];

  const float si0 = sself[bi * H + 0];
  const float si1 = sself[bi * H + 1];
  const float si2 = sself[bi * H + 2];
  const float si3 = sself[bi * H + 3];
  float den0 = 0.f, den1 = 0.f, den2 = 0.f, den3 = 0.f;
  float acc0 = 0.f, acc1 = 0.f;
  const unsigned long long lmlt = ((unsigned long long)1 << lane) - 1ull;
  const float* arow = a + (size_t)bi * N;
  const float* hb   = hfeat + (size_t)bbase * HID;
  const float* snb  = sneigh + (size_t)bbase * H;
  const int h0 = lane >> 5;
  int num = 0;

  auto flush = [&]() {
    asm volatile("s_waitcnt lgkmcnt(0)" ::: "memory");
    for (int n = lane; n < num; n += 64) {
      const int j = nb[n];
      f32x4 sn = *(const f32x4*)&snb[(size_t)j * H];
      float s0 = si0 + sn[0]; s0 = (s0 > 0.f) ? s0 : 0.2f * s0;
      float s1 = si1 + sn[1]; s1 = (s1 > 0.f) ? s1 : 0.2f * s1;
      float s2 = si2 + sn[2]; s2 = (s2 > 0.f) ? s2 : 0.2f * s2;
      float s3 = si3 + sn[3]; s3 = (s3 > 0.f) ? s3 : 0.2f * s3;
      float w0 = __expf(s0), w1 = __expf(s1), w2 = __expf(s2), w3 = __expf(s3);
      wt[n][0] = w0; wt[n][1] = w1; wt[n][2] = w2; wt[n][3] = w3;
      den0 += w0; den1 += w1; den2 += w2; den3 += w3;
    }
    asm volatile("s_waitcnt lgkmcnt(0)" ::: "memory");
    #pragma unroll 4
    for (int n = 0; n < num; ++n) {
      const int j  = nb[n];
      const float wA = wt[n][h0];
      const float wB = wt[n][h0 + 2];
      const float* hr = hb + (size_t)j * HID;
      acc0 += wA * hr[lane];
      acc1 += wB * hr[lane + 64];
    }
    asm volatile("s_waitcnt lgkmcnt(0)" ::: "memory");
    num = 0;
  };

  for (int jb = 0; jb < N; jb += 256) {
    f32x4 av = *(const f32x4*)&arow[jb + lane * 4];
    #pragma unroll
    for (int e = 0; e < 4; ++e) {
      const unsigned long long m = __ballot(av[e] > 0.5f);
      if (av[e] > 0.5f) {
        const int pos = num + __popcll(m & lmlt);
        nb[pos] = jb + lane * 4 + e;
      }
      num += __popcll(m);
      if (num > 192) flush();
    }
  }
  if (num > 0) flush();

  #pragma unroll
  for (int d = 32; d >= 1; d >>= 1) {
    den0 += __shfl_xor(den0, d, 64);
    den1 += __shfl_xor(den1, d, 64);
    den2 += __shfl_xor(den2, d, 64);
    den3 += __shfl_xor(den3, d, 64);
  }
  const float dA = h0 ? den1 : den0;
  const float dB = h0 ? den3 : den2;
  const float v0 = acc0 / dA + bias[lane];
  const float v1 = acc1 / dB + bias[64 + lane];
  { short hi, lo; split_bf16(v0, hi, lo);
    conv_hi[(size_t)bi * HID + lane] = hi; conv_lo[(size_t)bi * HID + lane] = lo; }
  { short hi, lo; split_bf16(v1, hi, lo);
    conv_hi[(size_t)bi * HID + 64 + lane] = hi; conv_lo[(size_t)bi * HID + 64 + lane] = lo; }
}

// ------------- shared arg pack -------------
struct GArgs {
  const short* chi; const short* clo;
  const float* h[3];
  const short* hhi[3]; const short* hlo[3];
  const float* bu[3]; const float* br[3]; const float* bc[3];
  const short* WuH[3]; const short* WuL[3];
  const short* WrH[3]; const short* WrL[3];
  const short* WcH[3]; const short* WcL[3];
  const short* RtH[3]; const short* RtL[3];
  float* u_ws[3];
  short* rhh[3]; short* rhl[3];
  short* hph[3]; short* hpl[3];
  float* hout[3]; __hip_bfloat16* hb[3]; __hip_bfloat16* gb[3];
};

// ------------- K3: u or r gate. 64 rows x 32 cols/block; async LDS weights -----
// grid (BN/64, 4 colgroups, 2 gates * 3 cells), 256 thr = 4 waves (16 rows each)
__global__ __launch_bounds__(256) void k_ur(GArgs ga) {
  const int wv = threadIdx.x >> 6, lane = threadIdx.x & 63;
  const int bx = blockIdx.x, cg = blockIdx.y;
  const int gate = blockIdx.z & 1, cell = blockIdx.z >> 1;
  const int lr = lane & 15, lg = lane >> 4, kb = lg * 8;
  const int R0 = bx * 64 + wv * 16;
  __shared__ short wlds[2][16][64][8];   // {hi,lo} x 16 frags = 32KB

  // A-fragments [conv | h] — 16 independent loads, issued first
  bf16x8 a_h[8], a_l[8];
  {
    const size_t ab = (size_t)(R0 + lr) * HID + kb;
    const short* hhi = ga.hhi[cell]; const short* hlo = ga.hlo[cell];
    #pragma unroll
    for (int ks = 0; ks < 4; ++ks) {
      a_h[ks]     = *(const bf16x8*)&ga.chi[ab + ks * 32];
      a_l[ks]     = *(const bf16x8*)&ga.clo[ab + ks * 32];
      a_h[4 + ks] = *(const bf16x8*)&hhi[ab + ks * 32];
      a_l[4 + ks] = *(const bf16x8*)&hlo[ab + ks * 32];
    }
  }
  // async weight staging: 32 frags, 8 per wave, zero VGPR round-trip
  {
    const short* WH = gate ? ga.WrH[cell] : ga.WuH[cell];
    const short* WL = gate ? ga.WrL[cell] : ga.WuL[cell];
    #pragma unroll
    for (int i = 0; i < 8; ++i) {
      const int fid = wv * 8 + i;
      const int combo = fid >> 4, f = fid & 15;
      const short* src = combo ? WL : WH;
      const short* gp = src + (((size_t)((cg * 2 + (f >> 3)) * 8 + (f & 7))) * 64 + lane) * 8;
      stage16(gp, &wlds[combo][f][0][0]);
    }
  }
  asm volatile("s_waitcnt vmcnt(0)" ::: "memory");
  __syncthreads();

  f32x4 acc[2] = {};
  #pragma unroll
  for (int ks = 0; ks < 8; ++ks) {
    const bf16x8 ah = a_h[ks], al = a_l[ks];
    #pragma unroll
    for (int cfl = 0; cfl < 2; ++cfl) {
      const int f = cfl * 8 + ks;
      bf16x8 bh = *(const bf16x8*)&wlds[0][f][lane][0];
      bf16x8 bl = *(const bf16x8*)&wlds[1][f][lane][0];
      acc[cfl] = __builtin_amdgcn_mfma_f32_16x16x32_bf16(ah, bh, acc[cfl], 0, 0, 0);
      acc[cfl] = __builtin_amdgcn_mfma_f32_16x16x32_bf16(ah, bl, acc[cfl], 0, 0, 0);
      acc[cfl] = __builtin_amdgcn_mfma_f32_16x16x32_bf16(al, bh, acc[cfl], 0, 0, 0);
    }
  }
  if (gate == 0) {
    const float* bu = ga.bu[cell];
    float* uws = ga.u_ws[cell];
    #pragma unroll
    for (int cfl = 0; cfl < 2; ++cfl) {
      const int col = cg * 32 + cfl * 16 + lr;
      #pragma unroll
      for (int q = 0; q < 4; ++q) {
        const int row = R0 + lg * 4 + q;
        uws[(size_t)row * HID + col] = sigmoidf_(acc[cfl][q] + bu[row & (N - 1)]);
      }
    }
  } else {
    const float* br = ga.br[cell];
    const float* hsrc = ga.h[cell];
    short* rhh = ga.rhh[cell]; short* rhl = ga.rhl[cell];
    #pragma unroll
    for (int cfl = 0; cfl < 2; ++cfl) {
      const int col = cg * 32 + cfl * 16 + lr;
      #pragma unroll
      for (int q = 0; q < 4; ++q) {
        const int row = R0 + lg * 4 + q;
        const float rv = sigmoidf_(acc[cfl][q] + br[row & (N - 1)]);
        const float rhv = rv * hsrc[(size_t)row * HID + col];
        short hi, lo; split_bf16(rhv, hi, lo);
        rhh[(size_t)row * HID + col] = hi;
        rhl[(size_t)row * HID + col] = lo;
      }
    }
  }
}

// ------------- K4: c gate + h'. 64 rows x 32 cols/block -------------
__global__ __launch_bounds__(256) void k_c(GArgs ga) {
  const int wv = threadIdx.x >> 6, lane = threadIdx.x & 63;
  const int bx = blockIdx.x, cg = blockIdx.y, cell = blockIdx.z;
  const int lr = lane & 15, lg = lane >> 4, kb = lg * 8;
  const int R0 = bx * 64 + wv * 16;
  __shared__ short wlds[2][16][64][8];   // 32KB

  bf16x8 a_h[8], a_l[8];
  {
    const size_t ab = (size_t)(R0 + lr) * HID + kb;
    const short* rhh = ga.rhh[cell]; const short* rhl = ga.rhl[cell];
    #pragma unroll
    for (int ks = 0; ks < 4; ++ks) {
      a_h[ks]     = *(const bf16x8*)&ga.chi[ab + ks * 32];
      a_l[ks]     = *(const bf16x8*)&ga.clo[ab + ks * 32];
      a_h[4 + ks] = *(const bf16x8*)&rhh[ab + ks * 32];
      a_l[4 + ks] = *(const bf16x8*)&rhl[ab + ks * 32];
    }
  }
  {
    const short* WH = ga.WcH[cell];
    const short* WL = ga.WcL[cell];
    #pragma unroll
    for (int i = 0; i < 8; ++i) {
      const int fid = wv * 8 + i;
      const int combo = fid >> 4, f = fid & 15;
      const short* src = combo ? WL : WH;
      const short* gp = src + (((size_t)((cg * 2 + (f >> 3)) * 8 + (f & 7))) * 64 + lane) * 8;
      stage16(gp, &wlds[combo][f][0][0]);
    }
  }
  asm volatile("s_waitcnt vmcnt(0)" ::: "memory");
  __syncthreads();

  f32x4 acc[2] = {};
  #pragma unroll
  for (int ks = 0; ks < 8; ++ks) {
    const bf16x8 ah = a_h[ks], al = a_l[ks];
    #pragma unroll
    for (int cfl = 0; cfl < 2; ++cfl) {
      const int f = cfl * 8 + ks;
      bf16x8 bh = *(const bf16x8*)&wlds[0][f][lane][0];
      bf16x8 bl = *(const bf16x8*)&wlds[1][f][lane][0];
      acc[cfl] = __builtin_amdgcn_mfma_f32_16x16x32_bf16(ah, bh, acc[cfl], 0, 0, 0);
      acc[cfl] = __builtin_amdgcn_mfma_f32_16x16x32_bf16(ah, bl, acc[cfl], 0, 0, 0);
      acc[cfl] = __builtin_amdgcn_mfma_f32_16x16x32_bf16(al, bh, acc[cfl], 0, 0, 0);
    }
  }
  const float* bc = ga.bc[cell];
  const float* uw = ga.u_ws[cell];
  const float* hsrc = ga.h[cell];
  float* hout = ga.hout[cell];
  __hip_bfloat16* hbo = ga.hb[cell];
  short* hph = ga.hph[cell]; short* hpl = ga.hpl[cell];
  #pragma unroll
  for (int cfl = 0; cfl < 2; ++cfl) {
    const int col = cg * 32 + cfl * 16 + lr;
    #pragma unroll
    for (int q = 0; q < 4; ++q) {
      const int row = R0 + lg * 4 + q;
      const float cv = tanhf_(acc[cfl][q] + bc[row & (N - 1)]);
      const float uv = uw[(size_t)row * HID + col];
      const float hv = hsrc[(size_t)row * HID + col];
      const float o = uv * hv + (1.f - uv) * cv;
      hout[(size_t)row * HID + col] = o;
      hbo[(size_t)row * HID + col] = __float2bfloat16(o);
      short hi, lo; split_bf16(o, hi, lo);
      hph[(size_t)row * HID + col] = hi;
      hpl[(size_t)row * HID + col] = lo;
    }
  }
}

// ------------- K5: g = h' @ R. 64 rows x 32 cols/block, K=128 -------------
__global__ __launch_bounds__(256) void k_g(GArgs ga) {
  const int wv = threadIdx.x >> 6, lane = threadIdx.x & 63;
  const int bx = blockIdx.x, cg = blockIdx.y, cell = blockIdx.z;
  const int lr = lane & 15, lg = lane >> 4, kb = lg * 8;
  const int R0 = bx * 64 + wv * 16;
  __shared__ short wlds[2][8][64][8];    // 16KB

  bf16x8 a_h[4], a_l[4];
  {
    const size_t ab = (size_t)(R0 + lr) * HID + kb;
    const short* hph = ga.hph[cell]; const short* hpl = ga.hpl[cell];
    #pragma unroll
    for (int ks = 0; ks < 4; ++ks) {
      a_h[ks] = *(const bf16x8*)&hph[ab + ks * 32];
      a_l[ks] = *(const bf16x8*)&hpl[ab + ks * 32];
    }
  }
  {
    #pragma unroll
    for (int i = 0; i < 4; ++i) {
      const int fid = wv * 4 + i;            // 0..15
      const int combo = fid >> 3, f = fid & 7;   // f = cfl*4+ks
      const short* src = combo ? ga.RtL[cell] : ga.RtH[cell];
      const short* gp = src + (((size_t)((cg * 2 + (f >> 2)) * 4 + (f & 3))) * 64 + lane) * 8;
      stage16(gp, &wlds[combo][f][0][0]);
    }
  }
  asm volatile("s_waitcnt vmcnt(0)" ::: "memory");
  __syncthreads();

  f32x4 acc[2] = {};
  #pragma unroll
  for (int ks = 0; ks < 4; ++ks) {
    const bf16x8 ah = a_h[ks], al = a_l[ks];
    #pragma unroll
    for (int cfl = 0; cfl < 2; ++cfl) {
      const int f = cfl * 4 + ks;
      bf16x8 bh = *(const bf16x8*)&wlds[0][f][lane][0];
      bf16x8 bl = *(const bf16x8*)&wlds[1][f][lane][0];
      acc[cfl] = __builtin_amdgcn_mfma_f32_16x16x32_bf16(ah, bh, acc[cfl], 0, 0, 0);
      acc[cfl] = __builtin_amdgcn_mfma_f32_16x16x32_bf16(ah, bl, acc[cfl], 0, 0, 0);
      acc[cfl] = __builtin_amdgcn_mfma_f32_16x16x32_bf16(al, bh, acc[cfl], 0, 0, 0);
    }
  }
  __hip_bfloat16* gbo = ga.gb[cell];
  #pragma unroll
  for (int cfl = 0; cfl < 2; ++cfl) {
    const int col = cg * 32 + cfl * 16 + lr;
    #pragma unroll
    for (int q = 0; q < 4; ++q) {
      const int row = R0 + lg * 4 + q;
      gbo[(size_t)row * HID + col] = __float2bfloat16(acc[cfl][q]);
    }
  }
}

// ------------- K6: logits[b,i,j,k] = g_k[b,i,:] . h_k[b,j,:]  (bf16 MFMA, NT) ---
__global__ __launch_bounds__(256) void k_bilinear(
    const __hip_bfloat16* __restrict__ g0, const __hip_bfloat16* __restrict__ g1,
    const __hip_bfloat16* __restrict__ g2, const __hip_bfloat16* __restrict__ h0,
    const __hip_bfloat16* __restrict__ h1, const __hip_bfloat16* __restrict__ h2,
    float* __restrict__ out) {
  const int ti = blockIdx.x, tj = blockIdx.y, b = blockIdx.z;
  const int t = threadIdx.x;
  const int w = t >> 6, l = t & 63;
  const int wi = w >> 1, wj = w & 1;
  const int i_base = ti * 64 + wi * 32;
  const int j_base = tj * 64 + wj * 32;
  const __hip_bfloat16* gbs[3] = {g0, g1, g2};
  const __hip_bfloat16* hbs[3] = {h0, h1, h2};
  const int lr = l & 15;
  const int kb = (l >> 4) * 8;
  f32x4 acc[3][2][2] = {};
  for (int k0 = 0; k0 < HID; k0 += 32) {
    bf16x8 af[3][2], bfr[3][2];
    #pragma unroll
    for (int d = 0; d < 3; ++d) {
      #pragma unroll
      for (int m = 0; m < 2; ++m) {
        af[d][m]  = *(const bf16x8*)&gbs[d][(size_t)(b * N + i_base + m * 16 + lr) * HID + k0 + kb];
        bfr[d][m] = *(const bf16x8*)&hbs[d][(size_t)(b * N + j_base + m * 16 + lr) * HID + k0 + kb];
      }
    }
    #pragma unroll
    for (int d = 0; d < 3; ++d)
      #pragma unroll
      for (int mi = 0; mi < 2; ++mi)
        #pragma unroll
        for (int mj = 0; mj < 2; ++mj)
          acc[d][mi][mj] = __builtin_amdgcn_mfma_f32_16x16x32_bf16(
              af[d][mi], bfr[d][mj], acc[d][mi][mj], 0, 0, 0);
  }
  const int orow = (l >> 4) * 4;
  const int col  = l & 15;
  #pragma unroll
  for (int mi = 0; mi < 2; ++mi)
    #pragma unroll
    for (int mj = 0; mj < 2; ++mj)
      #pragma unroll
      for (int r = 0; r < 4; ++r) {
        const int row = i_base + mi * 16 + orow + r;
        const int cc  = j_base + mj * 16 + col;
        float* p = &out[(((size_t)(b * N + row)) * N + cc) * 3];
        p[0] = acc[0][mi][mj][r];
        p[1] = acc[1][mi][mj][r];
        p[2] = acc[2][mi][mj][r];
      }
}

extern "C" void kernel_launch(void* const* d_in, const int* in_sizes, int n_in,
                              void* d_out, int out_size, void* d_ws, size_t ws_size,
                              hipStream_t stream) {
  (void)in_sizes; (void)n_in; (void)out_size; (void)ws_size;
  const float* a    = (const float*)d_in[1];
  const float* bias = (const float*)d_in[8];

  float* ws      = (float*)d_ws;
  float* hfeat   = ws;                                    // BN*HID f32
  float* sself   = hfeat + (size_t)BN * HID;
  float* sneigh  = sself + (size_t)BN * H;
  float* u_ws0   = sneigh + (size_t)BN * H;               // 3 * BN*HID f32
  short* sp      = (short*)(u_ws0 + 3 * (size_t)BN * HID);
  auto alloc_s = [&](size_t n) { short* p = sp; sp += n; return p; };

  short* conv_hi = alloc_s((size_t)BN * HID);
  short* conv_lo = alloc_s((size_t)BN * HID);
  short* h_hi[3]; short* h_lo[3];
  for (int c = 0; c < 3; ++c) { h_hi[c] = alloc_s((size_t)BN * HID); h_lo[c] = alloc_s((size_t)BN * HID); }
  short* rh_hi[3]; short* rh_lo[3];
  for (int c = 0; c < 3; ++c) { rh_hi[c] = alloc_s((size_t)BN * HID); rh_lo[c] = alloc_s((size_t)BN * HID); }
  short* hp_hi[3]; short* hp_lo[3];
  for (int c = 0; c < 3; ++c) { hp_hi[c] = alloc_s((size_t)BN * HID); hp_lo[c] = alloc_s((size_t)BN * HID); }
  __hip_bfloat16* hbb[3]; __hip_bfloat16* gbb[3];
  for (int c = 0; c < 3; ++c) {
    hbb[c] = (__hip_bfloat16*)alloc_s((size_t)BN * HID);
    gbb[c] = (__hip_bfloat16*)alloc_s((size_t)BN * HID);
  }

  float* out = (float*)d_out;

  PreArgs pa;
  pa.x = (const float*)d_in[0];
  pa.gk = (const float*)d_in[5];
  pa.asel = (const float*)d_in[6];
  pa.anei = (const float*)d_in[7];
  pa.hfeat = hfeat; pa.sself = sself; pa.sneigh = sneigh;

  GArgs ga;
  ga.chi = conv_hi; ga.clo = conv_lo;
  ga.h[0] = (const float*)d_in[2];
  ga.h[1] = (const float*)d_in[3];
  ga.h[2] = (const float*)d_in[4];
  for (int c = 0; c < 3; ++c) {
    pa.h[c] = ga.h[c];
    pa.hh[c] = h_hi[c]; pa.hl[c] = h_lo[c];
    const int base = 9 + c * 6;
    ga.hhi[c] = h_hi[c]; ga.hlo[c] = h_lo[c];
    ga.bu[c] = (const float*)d_in[base + 1];
    ga.br[c] = (const float*)d_in[base + 3];
    ga.bc[c] = (const float*)d_in[base + 5];
    short* wu_h = alloc_s(256 * 128); short* wu_l = alloc_s(256 * 128);
    short* wr_h = alloc_s(256 * 128); short* wr_l = alloc_s(256 * 128);
    short* wc_h = alloc_s(256 * 128); short* wc_l = alloc_s(256 * 128);
    short* rt_h = alloc_s(128 * 128); short* rt_l = alloc_s(128 * 128);
    const int pb = c * 4;
    pa.src[pb + 0] = (const float*)d_in[base + 0]; pa.whi[pb + 0] = wu_h; pa.wlo[pb + 0] = wu_l; pa.nks[pb + 0] = 8;
    pa.src[pb + 1] = (const float*)d_in[base + 2]; pa.whi[pb + 1] = wr_h; pa.wlo[pb + 1] = wr_l; pa.nks[pb + 1] = 8;
    pa.src[pb + 2] = (const float*)d_in[base + 4]; pa.whi[pb + 2] = wc_h; pa.wlo[pb + 2] = wc_l; pa.nks[pb + 2] = 8;
    pa.src[pb + 3] = (const float*)d_in[27 + c];   pa.whi[pb + 3] = rt_h; pa.wlo[pb + 3] = rt_l; pa.nks[pb + 3] = 4;
    ga.WuH[c] = wu_h; ga.WuL[c] = wu_l;
    ga.WrH[c] = wr_h; ga.WrL[c] = wr_l;
    ga.WcH[c] = wc_h; ga.WcL[c] = wc_l;
    ga.RtH[c] = rt_h; ga.RtL[c] = rt_l;
    ga.u_ws[c] = u_ws0 + (size_t)c * BN * HID;
    ga.rhh[c] = rh_hi[c]; ga.rhl[c] = rh_lo[c];
    ga.hph[c] = hp_hi[c]; ga.hpl[c] = hp_lo[c];
    ga.hout[c] = out + LOG_SZ + (size_t)c * BN * HID;
    ga.hb[c] = hbb[c];
    ga.gb[c] = gbb[c];
  }

  k_pre<<<BN / 2 + 96, 256, 0, stream>>>(pa);
  k_attn<<<BN / 4, 256, 0, stream>>>(a, hfeat, sself, sneigh, bias, conv_hi, conv_lo);
  k_ur<<<dim3(BN / 64, 4, 6), 256, 0, stream>>>(ga);
  k_c<<<dim3(BN / 64, 4, 3), 256, 0, stream>>>(ga);
  k_g<<<dim3(BN / 64, 4, 3), 256, 0, stream>>>(ga);
  dim3 g2(N / 64, N / 64, B);
  k_bilinear<<<g2, 256, 0, stream>>>(gbb[0], gbb[1], gbb[2],
                                     hbb[0], hbb[1], hbb[2], out);
}

// Round 8
// 115.277 us; speedup vs baseline: 1.2950x; 1.0091x over previous
//
#include <hip/hip_runtime.h>
#include <hip/hip_bf16.h>

typedef __attribute__((ext_vector_type(4))) float f32x4;
typedef __attribute__((ext_vector_type(8))) short bf16x8;

static constexpr int B   = 2;
static constexpr int N   = 2048;
static constexpr int F   = 64;
static constexpr int H   = 4;
static constexpr int HID = 128;
static constexpr int BN  = B * N;
static constexpr size_t LOG_SZ = (size_t)B * N * N * 3;

__device__ __forceinline__ float sigmoidf_(float x) { return 1.0f / (1.0f + __expf(-x)); }
__device__ __forceinline__ float tanhf_(float x) {
  float e = __expf(2.0f * x);
  return 1.0f - 2.0f / (e + 1.0f);      // inf-safe
}
// RNE bf16 split: v = hi + lo with ~2^-17 relative error
__device__ __forceinline__ void split_bf16(float v, short& hi, short& lo) {
  unsigned u = __float_as_uint(v);
  unsigned hr = (u + 0x7FFFu + ((u >> 16) & 1u)) >> 16;
  hi = (short)hr;
  float hv = __uint_as_float(hr << 16);
  float res = v - hv;
  unsigned u2 = __float_as_uint(res);
  lo = (short)((u2 + 0x7FFFu + ((u2 >> 16) & 1u)) >> 16);
}

__device__ __forceinline__ void stage16(const short* gp, short* lp) {
  __builtin_amdgcn_global_load_lds(
      (const __attribute__((address_space(1))) void*)gp,
      (__attribute__((address_space(3))) void*)lp, 16, 0, 0);
}

// ------------- K1: merged prep (weights->frag-order bf16x2) + feat + h-split ---
struct PreArgs {
  const float* x; const float* gk; const float* asel; const float* anei;
  float* hfeat; float* sself; float* sneigh;
  const float* h[3];
  short* hh[3]; short* hl[3];
  const float* src[12];
  short* whi[12]; short* wlo[12];
  int nks[12];               // 8 for W (K=256), 4 for R (K=128)
};
__global__ __launch_bounds__(256) void k_pre(PreArgs pa) {
  const int bid = blockIdx.x;
  if (bid < BN / 2) {
    const int t = threadIdx.x;
    const int r = t >> 7, tt = t & 127;
    const int bn = bid * 2 + r;
    __shared__ float xs[2][F];
    if (tt < F) xs[r][tt] = pa.x[(size_t)bn * F + tt];
    const size_t o = (size_t)bn * HID + tt;
    { short hi, lo; split_bf16(pa.h[0][o], hi, lo); pa.hh[0][o] = hi; pa.hl[0][o] = lo; }
    { short hi, lo; split_bf16(pa.h[1][o], hi, lo); pa.hh[1][o] = hi; pa.hl[1][o] = lo; }
    { short hi, lo; split_bf16(pa.h[2][o], hi, lo); pa.hh[2][o] = hi; pa.hl[2][o] = lo; }
    __syncthreads();
    float acc = 0.f;
    #pragma unroll 8
    for (int f = 0; f < F; ++f) acc += xs[r][f] * pa.gk[f * HID + tt];
    pa.hfeat[o] = acc;
    float ps = acc * pa.asel[tt];
    float pn = acc * pa.anei[tt];
    #pragma unroll
    for (int d = 16; d >= 1; d >>= 1) {
      ps += __shfl_xor(ps, d, 32);
      pn += __shfl_xor(pn, d, 32);
    }
    if ((tt & 31) == 0) {
      pa.sself [bn * H + (tt >> 5)] = ps;
      pa.sneigh[bn * H + (tt >> 5)] = pn;
    }
  } else {
    const int pb = bid - BN / 2;         // 0..95
    const int m = pb >> 3, cf = pb & 7;
    const int nksv = pa.nks[m];
    const int wv = threadIdx.x >> 6, lane = threadIdx.x & 63;
    const float* src = pa.src[m];
    short* ph = pa.whi[m];
    short* pl = pa.wlo[m];
    const int col = cf * 16 + (lane & 15);
    const int krow = (lane >> 4) * 8;
    for (int ks = wv; ks < nksv; ks += 4) {
      bf16x8 vh, vl;
      #pragma unroll
      for (int e = 0; e < 8; ++e) {
        const int k = ks * 32 + krow + e;
        short hi, lo; split_bf16(src[(size_t)k * HID + col], hi, lo);
        vh[e] = hi; vl[e] = lo;
      }
      const size_t o = (((size_t)cf * nksv + ks) * 64 + lane) * 8;
      *(bf16x8*)&ph[o] = vh;
      *(bf16x8*)&pl[o] = vl;
    }
  }
}

// ------------- K2: sparse GAT attention — 1 row/block, 4 waves split neighbors --
__global__ __launch_bounds__(256) void k_attn(
    const float* __restrict__ a, const float* __restrict__ hfeat,
    const float* __restrict__ sself, const float* __restrict__ sneigh,
    const float* __restrict__ bias,
    short* __restrict__ conv_hi, short* __restrict__ conv_lo) {
  const int wv   = threadIdx.x >> 6;
  const int lane = threadIdx.x & 63;
  const int bi   = blockIdx.x;
  const int bbase = bi & ~(N - 1);
  __shared__ int   nbr[4][128];
  __shared__ float wts[4][128][4];
  __shared__ float racc[4][128];
  __shared__ float rden[4][4];
  int*   nb      = nbr[wv];
  float (*wt)[4] = wts[wv];

  const float si0 = sself[bi * H + 0];
  const float si1 = sself[bi * H + 1];
  const float si2 = sself[bi * H + 2];
  const float si3 = sself[bi * H + 3];
  float den0 = 0.f, den1 = 0.f, den2 = 0.f, den3 = 0.f;
  float acc0 = 0.f, acc1 = 0.f;
  const unsigned long long lmlt = ((unsigned long long)1 << lane) - 1ull;
  const float* arow = a + (size_t)bi * N + wv * 512;   // wave's quarter
  const float* hb   = hfeat + (size_t)bbase * HID;
  const float* snb  = sneigh + (size_t)bbase * H;
  const int h0 = lane >> 5;
  const int jbase0 = wv * 512;
  int num = 0;

  auto flush = [&]() {
    asm volatile("s_waitcnt lgkmcnt(0)" ::: "memory");
    for (int n = lane; n < num; n += 64) {
      const int j = nb[n];
      f32x4 sn = *(const f32x4*)&snb[(size_t)j * H];
      float s0 = si0 + sn[0]; s0 = (s0 > 0.f) ? s0 : 0.2f * s0;
      float s1 = si1 + sn[1]; s1 = (s1 > 0.f) ? s1 : 0.2f * s1;
      float s2 = si2 + sn[2]; s2 = (s2 > 0.f) ? s2 : 0.2f * s2;
      float s3 = si3 + sn[3]; s3 = (s3 > 0.f) ? s3 : 0.2f * s3;
      float w0 = __expf(s0), w1 = __expf(s1), w2 = __expf(s2), w3 = __expf(s3);
      wt[n][0] = w0; wt[n][1] = w1; wt[n][2] = w2; wt[n][3] = w3;
      den0 += w0; den1 += w1; den2 += w2; den3 += w3;
    }
    asm volatile("s_waitcnt lgkmcnt(0)" ::: "memory");
    #pragma unroll 4
    for (int n = 0; n < num; ++n) {
      const int j  = nb[n];
      const float wA = wt[n][h0];
      const float wB = wt[n][h0 + 2];
      const float* hr = hb + (size_t)j * HID;
      acc0 += wA * hr[lane];
      acc1 += wB * hr[lane + 64];
    }
    asm volatile("s_waitcnt lgkmcnt(0)" ::: "memory");
    num = 0;
  };

  #pragma unroll
  for (int jb = 0; jb < 512; jb += 256) {
    f32x4 av = *(const f32x4*)&arow[jb + lane * 4];
    #pragma unroll
    for (int e = 0; e < 4; ++e) {
      const unsigned long long m = __ballot(av[e] > 0.5f);
      if (av[e] > 0.5f) {
        const int pos = num + __popcll(m & lmlt);
        nb[pos] = jbase0 + jb + lane * 4 + e;
      }
      num += __popcll(m);
      if (num > 64) flush();             // wave-uniform; cap 128 never exceeded
    }
  }
  if (num > 0) flush();

  #pragma unroll
  for (int d = 32; d >= 1; d >>= 1) {
    den0 += __shfl_xor(den0, d, 64);
    den1 += __shfl_xor(den1, d, 64);
    den2 += __shfl_xor(den2, d, 64);
    den3 += __shfl_xor(den3, d, 64);
  }
  racc[wv][lane]      = acc0;
  racc[wv][lane + 64] = acc1;
  if (lane == 0) {
    rden[wv][0] = den0; rden[wv][1] = den1;
    rden[wv][2] = den2; rden[wv][3] = den3;
  }
  __syncthreads();
  if (threadIdx.x < HID) {
    const int ch = threadIdx.x;
    const float tot = racc[0][ch] + racc[1][ch] + racc[2][ch] + racc[3][ch];
    const int hh = ch >> 5;
    const float dd = rden[0][hh] + rden[1][hh] + rden[2][hh] + rden[3][hh];
    const float v = tot / dd + bias[ch];
    short hi, lo; split_bf16(v, hi, lo);
    conv_hi[(size_t)bi * HID + ch] = hi;
    conv_lo[(size_t)bi * HID + ch] = lo;
  }
}

// ------------- shared arg pack -------------
struct GArgs {
  const short* chi; const short* clo;
  const float* h[3];
  const short* hhi[3]; const short* hlo[3];
  const float* bu[3]; const float* br[3]; const float* bc[3];
  const short* WuH[3]; const short* WuL[3];
  const short* WrH[3]; const short* WrL[3];
  const short* WcH[3]; const short* WcL[3];
  const short* RtH[3]; const short* RtL[3];
  float* u_ws[3];
  short* rhh[3]; short* rhl[3];
  short* hph[3]; short* hpl[3];
  float* hout[3]; __hip_bfloat16* hb[3]; __hip_bfloat16* gb[3];
};

// ------------- K3: u or r gate. 64 rows x 32 cols/block; async LDS weights -----
__global__ __launch_bounds__(256) void k_ur(GArgs ga) {
  const int wv = threadIdx.x >> 6, lane = threadIdx.x & 63;
  const int bx = blockIdx.x, cg = blockIdx.y;
  const int gate = blockIdx.z & 1, cell = blockIdx.z >> 1;
  const int lr = lane & 15, lg = lane >> 4, kb = lg * 8;
  const int R0 = bx * 64 + wv * 16;
  __shared__ short wlds[2][16][64][8];   // {hi,lo} x 16 frags = 32KB

  bf16x8 a_h[8], a_l[8];
  {
    const size_t ab = (size_t)(R0 + lr) * HID + kb;
    const short* hhi = ga.hhi[cell]; const short* hlo = ga.hlo[cell];
    #pragma unroll
    for (int ks = 0; ks < 4; ++ks) {
      a_h[ks]     = *(const bf16x8*)&ga.chi[ab + ks * 32];
      a_l[ks]     = *(const bf16x8*)&ga.clo[ab + ks * 32];
      a_h[4 + ks] = *(const bf16x8*)&hhi[ab + ks * 32];
      a_l[4 + ks] = *(const bf16x8*)&hlo[ab + ks * 32];
    }
  }
  {
    const short* WH = gate ? ga.WrH[cell] : ga.WuH[cell];
    const short* WL = gate ? ga.WrL[cell] : ga.WuL[cell];
    #pragma unroll
    for (int i = 0; i < 8; ++i) {
      const int fid = wv * 8 + i;
      const int combo = fid >> 4, f = fid & 15;
      const short* src = combo ? WL : WH;
      const short* gp = src + (((size_t)((cg * 2 + (f >> 3)) * 8 + (f & 7))) * 64 + lane) * 8;
      stage16(gp, &wlds[combo][f][0][0]);
    }
  }
  asm volatile("s_waitcnt vmcnt(0)" ::: "memory");
  __syncthreads();

  f32x4 acc[2] = {};
  #pragma unroll
  for (int ks = 0; ks < 8; ++ks) {
    const bf16x8 ah = a_h[ks], al = a_l[ks];
    #pragma unroll
    for (int cfl = 0; cfl < 2; ++cfl) {
      const int f = cfl * 8 + ks;
      bf16x8 bh = *(const bf16x8*)&wlds[0][f][lane][0];
      bf16x8 bl = *(const bf16x8*)&wlds[1][f][lane][0];
      acc[cfl] = __builtin_amdgcn_mfma_f32_16x16x32_bf16(ah, bh, acc[cfl], 0, 0, 0);
      acc[cfl] = __builtin_amdgcn_mfma_f32_16x16x32_bf16(ah, bl, acc[cfl], 0, 0, 0);
      acc[cfl] = __builtin_amdgcn_mfma_f32_16x16x32_bf16(al, bh, acc[cfl], 0, 0, 0);
    }
  }
  if (gate == 0) {
    const float* bu = ga.bu[cell];
    float* uws = ga.u_ws[cell];
    #pragma unroll
    for (int cfl = 0; cfl < 2; ++cfl) {
      const int col = cg * 32 + cfl * 16 + lr;
      #pragma unroll
      for (int q = 0; q < 4; ++q) {
        const int row = R0 + lg * 4 + q;
        uws[(size_t)row * HID + col] = sigmoidf_(acc[cfl][q] + bu[row & (N - 1)]);
      }
    }
  } else {
    const float* br = ga.br[cell];
    const float* hsrc = ga.h[cell];
    short* rhh = ga.rhh[cell]; short* rhl = ga.rhl[cell];
    #pragma unroll
    for (int cfl = 0; cfl < 2; ++cfl) {
      const int col = cg * 32 + cfl * 16 + lr;
      #pragma unroll
      for (int q = 0; q < 4; ++q) {
        const int row = R0 + lg * 4 + q;
        const float rv = sigmoidf_(acc[cfl][q] + br[row & (N - 1)]);
        const float rhv = rv * hsrc[(size_t)row * HID + col];
        short hi, lo; split_bf16(rhv, hi, lo);
        rhh[(size_t)row * HID + col] = hi;
        rhl[(size_t)row * HID + col] = lo;
      }
    }
  }
}

// ------------- K4: c gate + h'. 64 rows x 32 cols/block -------------
__global__ __launch_bounds__(256) void k_c(GArgs ga) {
  const int wv = threadIdx.x >> 6, lane = threadIdx.x & 63;
  const int bx = blockIdx.x, cg = blockIdx.y, cell = blockIdx.z;
  const int lr = lane & 15, lg = lane >> 4, kb = lg * 8;
  const int R0 = bx * 64 + wv * 16;
  __shared__ short wlds[2][16][64][8];   // 32KB

  bf16x8 a_h[8], a_l[8];
  {
    const size_t ab = (size_t)(R0 + lr) * HID + kb;
    const short* rhh = ga.rhh[cell]; const short* rhl = ga.rhl[cell];
    #pragma unroll
    for (int ks = 0; ks < 4; ++ks) {
      a_h[ks]     = *(const bf16x8*)&ga.chi[ab + ks * 32];
      a_l[ks]     = *(const bf16x8*)&ga.clo[ab + ks * 32];
      a_h[4 + ks] = *(const bf16x8*)&rhh[ab + ks * 32];
      a_l[4 + ks] = *(const bf16x8*)&rhl[ab + ks * 32];
    }
  }
  {
    const short* WH = ga.WcH[cell];
    const short* WL = ga.WcL[cell];
    #pragma unroll
    for (int i = 0; i < 8; ++i) {
      const int fid = wv * 8 + i;
      const int combo = fid >> 4, f = fid & 15;
      const short* src = combo ? WL : WH;
      const short* gp = src + (((size_t)((cg * 2 + (f >> 3)) * 8 + (f & 7))) * 64 + lane) * 8;
      stage16(gp, &wlds[combo][f][0][0]);
    }
  }
  asm volatile("s_waitcnt vmcnt(0)" ::: "memory");
  __syncthreads();

  f32x4 acc[2] = {};
  #pragma unroll
  for (int ks = 0; ks < 8; ++ks) {
    const bf16x8 ah = a_h[ks], al = a_l[ks];
    #pragma unroll
    for (int cfl = 0; cfl < 2; ++cfl) {
      const int f = cfl * 8 + ks;
      bf16x8 bh = *(const bf16x8*)&wlds[0][f][lane][0];
      bf16x8 bl = *(const bf16x8*)&wlds[1][f][lane][0];
      acc[cfl] = __builtin_amdgcn_mfma_f32_16x16x32_bf16(ah, bh, acc[cfl], 0, 0, 0);
      acc[cfl] = __builtin_amdgcn_mfma_f32_16x16x32_bf16(ah, bl, acc[cfl], 0, 0, 0);
      acc[cfl] = __builtin_amdgcn_mfma_f32_16x16x32_bf16(al, bh, acc[cfl], 0, 0, 0);
    }
  }
  const float* bc = ga.bc[cell];
  const float* uw = ga.u_ws[cell];
  const float* hsrc = ga.h[cell];
  float* hout = ga.hout[cell];
  __hip_bfloat16* hbo = ga.hb[cell];
  short* hph = ga.hph[cell]; short* hpl = ga.hpl[cell];
  #pragma unroll
  for (int cfl = 0; cfl < 2; ++cfl) {
    const int col = cg * 32 + cfl * 16 + lr;
    #pragma unroll
    for (int q = 0; q < 4; ++q) {
      const int row = R0 + lg * 4 + q;
      const float cv = tanhf_(acc[cfl][q] + bc[row & (N - 1)]);
      const float uv = uw[(size_t)row * HID + col];
      const float hv = hsrc[(size_t)row * HID + col];
      const float o = uv * hv + (1.f - uv) * cv;
      __builtin_nontemporal_store(o, &hout[(size_t)row * HID + col]);
      hbo[(size_t)row * HID + col] = __float2bfloat16(o);
      short hi, lo; split_bf16(o, hi, lo);
      hph[(size_t)row * HID + col] = hi;
      hpl[(size_t)row * HID + col] = lo;
    }
  }
}

// ------------- K5: g = h' @ R. 64 rows x 32 cols/block, K=128 -------------
__global__ __launch_bounds__(256) void k_g(GArgs ga) {
  const int wv = threadIdx.x >> 6, lane = threadIdx.x & 63;
  const int bx = blockIdx.x, cg = blockIdx.y, cell = blockIdx.z;
  const int lr = lane & 15, lg = lane >> 4, kb = lg * 8;
  const int R0 = bx * 64 + wv * 16;
  __shared__ short wlds[2][8][64][8];    // 16KB

  bf16x8 a_h[4], a_l[4];
  {
    const size_t ab = (size_t)(R0 + lr) * HID + kb;
    const short* hph = ga.hph[cell]; const short* hpl = ga.hpl[cell];
    #pragma unroll
    for (int ks = 0; ks < 4; ++ks) {
      a_h[ks] = *(const bf16x8*)&hph[ab + ks * 32];
      a_l[ks] = *(const bf16x8*)&hpl[ab + ks * 32];
    }
  }
  {
    #pragma unroll
    for (int i = 0; i < 4; ++i) {
      const int fid = wv * 4 + i;            // 0..15
      const int combo = fid >> 3, f = fid & 7;   // f = cfl*4+ks
      const short* src = combo ? ga.RtL[cell] : ga.RtH[cell];
      const short* gp = src + (((size_t)((cg * 2 + (f >> 2)) * 4 + (f & 3))) * 64 + lane) * 8;
      stage16(gp, &wlds[combo][f][0][0]);
    }
  }
  asm volatile("s_waitcnt vmcnt(0)" ::: "memory");
  __syncthreads();

  f32x4 acc[2] = {};
  #pragma unroll
  for (int ks = 0; ks < 4; ++ks) {
    const bf16x8 ah = a_h[ks], al = a_l[ks];
    #pragma unroll
    for (int cfl = 0; cfl < 2; ++cfl) {
      const int f = cfl * 4 + ks;
      bf16x8 bh = *(const bf16x8*)&wlds[0][f][lane][0];
      bf16x8 bl = *(const bf16x8*)&wlds[1][f][lane][0];
      acc[cfl] = __builtin_amdgcn_mfma_f32_16x16x32_bf16(ah, bh, acc[cfl], 0, 0, 0);
      acc[cfl] = __builtin_amdgcn_mfma_f32_16x16x32_bf16(ah, bl, acc[cfl], 0, 0, 0);
      acc[cfl] = __builtin_amdgcn_mfma_f32_16x16x32_bf16(al, bh, acc[cfl], 0, 0, 0);
    }
  }
  __hip_bfloat16* gbo = ga.gb[cell];
  #pragma unroll
  for (int cfl = 0; cfl < 2; ++cfl) {
    const int col = cg * 32 + cfl * 16 + lr;
    #pragma unroll
    for (int q = 0; q < 4; ++q) {
      const int row = R0 + lg * 4 + q;
      gbo[(size_t)row * HID + col] = __float2bfloat16(acc[cfl][q]);
    }
  }
}

// ------------- K6: logits[b,i,j,k] = g_k[b,i,:] . h_k[b,j,:]  (bf16 MFMA, NT) ---
__global__ __launch_bounds__(256) void k_bilinear(
    const __hip_bfloat16* __restrict__ g0, const __hip_bfloat16* __restrict__ g1,
    const __hip_bfloat16* __restrict__ g2, const __hip_bfloat16* __restrict__ h0,
    const __hip_bfloat16* __restrict__ h1, const __hip_bfloat16* __restrict__ h2,
    float* __restrict__ out) {
  const int ti = blockIdx.x, tj = blockIdx.y, b = blockIdx.z;
  const int t = threadIdx.x;
  const int w = t >> 6, l = t & 63;
  const int wi = w >> 1, wj = w & 1;
  const int i_base = ti * 64 + wi * 32;
  const int j_base = tj * 64 + wj * 32;
  const __hip_bfloat16* gbs[3] = {g0, g1, g2};
  const __hip_bfloat16* hbs[3] = {h0, h1, h2};
  const int lr = l & 15;
  const int kb = (l >> 4) * 8;
  f32x4 acc[3][2][2] = {};
  for (int k0 = 0; k0 < HID; k0 += 32) {
    bf16x8 af[3][2], bfr[3][2];
    #pragma unroll
    for (int d = 0; d < 3; ++d) {
      #pragma unroll
      for (int m = 0; m < 2; ++m) {
        af[d][m]  = *(const bf16x8*)&gbs[d][(size_t)(b * N + i_base + m * 16 + lr) * HID + k0 + kb];
        bfr[d][m] = *(const bf16x8*)&hbs[d][(size_t)(b * N + j_base + m * 16 + lr) * HID + k0 + kb];
      }
    }
    #pragma unroll
    for (int d = 0; d < 3; ++d)
      #pragma unroll
      for (int mi = 0; mi < 2; ++mi)
        #pragma unroll
        for (int mj = 0; mj < 2; ++mj)
          acc[d][mi][mj] = __builtin_amdgcn_mfma_f32_16x16x32_bf16(
              af[d][mi], bfr[d][mj], acc[d][mi][mj], 0, 0, 0);
  }
  const int orow = (l >> 4) * 4;
  const int col  = l & 15;
  #pragma unroll
  for (int mi = 0; mi < 2; ++mi)
    #pragma unroll
    for (int mj = 0; mj < 2; ++mj)
      #pragma unroll
      for (int r = 0; r < 4; ++r) {
        const int row = i_base + mi * 16 + orow + r;
        const int cc  = j_base + mj * 16 + col;
        float* p = &out[(((size_t)(b * N + row)) * N + cc) * 3];
        __builtin_nontemporal_store(acc[0][mi][mj][r], p + 0);
        __builtin_nontemporal_store(acc[1][mi][mj][r], p + 1);
        __builtin_nontemporal_store(acc[2][mi][mj][r], p + 2);
      }
}

extern "C" void kernel_launch(void* const* d_in, const int* in_sizes, int n_in,
                              void* d_out, int out_size, void* d_ws, size_t ws_size,
                              hipStream_t stream) {
  (void)in_sizes; (void)n_in; (void)out_size; (void)ws_size;
  const float* a    = (const float*)d_in[1];
  const float* bias = (const float*)d_in[8];

  float* ws      = (float*)d_ws;
  float* hfeat   = ws;                                    // BN*HID f32
  float* sself   = hfeat + (size_t)BN * HID;
  float* sneigh  = sself + (size_t)BN * H;
  float* u_ws0   = sneigh + (size_t)BN * H;               // 3 * BN*HID f32
  short* sp      = (short*)(u_ws0 + 3 * (size_t)BN * HID);
  auto alloc_s = [&](size_t n) { short* p = sp; sp += n; return p; };

  short* conv_hi = alloc_s((size_t)BN * HID);
  short* conv_lo = alloc_s((size_t)BN * HID);
  short* h_hi[3]; short* h_lo[3];
  for (int c = 0; c < 3; ++c) { h_hi[c] = alloc_s((size_t)BN * HID); h_lo[c] = alloc_s((size_t)BN * HID); }
  short* rh_hi[3]; short* rh_lo[3];
  for (int c = 0; c < 3; ++c) { rh_hi[c] = alloc_s((size_t)BN * HID); rh_lo[c] = alloc_s((size_t)BN * HID); }
  short* hp_hi[3]; short* hp_lo[3];
  for (int c = 0; c < 3; ++c) { hp_hi[c] = alloc_s((size_t)BN * HID); hp_lo[c] = alloc_s((size_t)BN * HID); }
  __hip_bfloat16* hbb[3]; __hip_bfloat16* gbb[3];
  for (int c = 0; c < 3; ++c) {
    hbb[c] = (__hip_bfloat16*)alloc_s((size_t)BN * HID);
    gbb[c] = (__hip_bfloat16*)alloc_s((size_t)BN * HID);
  }

  float* out = (float*)d_out;

  PreArgs pa;
  pa.x = (const float*)d_in[0];
  pa.gk = (const float*)d_in[5];
  pa.asel = (const float*)d_in[6];
  pa.anei = (const float*)d_in[7];
  pa.hfeat = hfeat; pa.sself = sself; pa.sneigh = sneigh;

  GArgs ga;
  ga.chi = conv_hi; ga.clo = conv_lo;
  ga.h[0] = (const float*)d_in[2];
  ga.h[1] = (const float*)d_in[3];
  ga.h[2] = (const float*)d_in[4];
  for (int c = 0; c < 3; ++c) {
    pa.h[c] = ga.h[c];
    pa.hh[c] = h_hi[c]; pa.hl[c] = h_lo[c];
    const int base = 9 + c * 6;
    ga.hhi[c] = h_hi[c]; ga.hlo[c] = h_lo[c];
    ga.bu[c] = (const float*)d_in[base + 1];
    ga.br[c] = (const float*)d_in[base + 3];
    ga.bc[c] = (const float*)d_in[base + 5];
    short* wu_h = alloc_s(256 * 128); short* wu_l = alloc_s(256 * 128);
    short* wr_h = alloc_s(256 * 128); short* wr_l = alloc_s(256 * 128);
    short* wc_h = alloc_s(256 * 128); short* wc_l = alloc_s(256 * 128);
    short* rt_h = alloc_s(128 * 128); short* rt_l = alloc_s(128 * 128);
    const int pb = c * 4;
    pa.src[pb + 0] = (const float*)d_in[base + 0]; pa.whi[pb + 0] = wu_h; pa.wlo[pb + 0] = wu_l; pa.nks[pb + 0] = 8;
    pa.src[pb + 1] = (const float*)d_in[base + 2]; pa.whi[pb + 1] = wr_h; pa.wlo[pb + 1] = wr_l; pa.nks[pb + 1] = 8;
    pa.src[pb + 2] = (const float*)d_in[base + 4]; pa.whi[pb + 2] = wc_h; pa.wlo[pb + 2] = wc_l; pa.nks[pb + 2] = 8;
    pa.src[pb + 3] = (const float*)d_in[27 + c];   pa.whi[pb + 3] = rt_h; pa.wlo[pb + 3] = rt_l; pa.nks[pb + 3] = 4;
    ga.WuH[c] = wu_h; ga.WuL[c] = wu_l;
    ga.WrH[c] = wr_h; ga.WrL[c] = wr_l;
    ga.WcH[c] = wc_h; ga.WcL[c] = wc_l;
    ga.RtH[c] = rt_h; ga.RtL[c] = rt_l;
    ga.u_ws[c] = u_ws0 + (size_t)c * BN * HID;
    ga.rhh[c] = rh_hi[c]; ga.rhl[c] = rh_lo[c];
    ga.hph[c] = hp_hi[c]; ga.hpl[c] = hp_lo[c];
    ga.hout[c] = out + LOG_SZ + (size_t)c * BN * HID;
    ga.hb[c] = hbb[c];
    ga.gb[c] = gbb[c];
  }

  k_pre<<<BN / 2 + 96, 256, 0, stream>>>(pa);
  k_attn<<<BN, 256, 0, stream>>>(a, hfeat, sself, sneigh, bias, conv_hi, conv_lo);
  k_ur<<<dim3(BN / 64, 4, 6), 256, 0, stream>>>(ga);
  k_c<<<dim3(BN / 64, 4, 3), 256, 0, stream>>>(ga);
  k_g<<<dim3(BN / 64, 4, 3), 256, 0, stream>>>(ga);
  dim3 g2(N / 64, N / 64, B);
  k_bilinear<<<g2, 256, 0, stream>>>(gbb[0], gbb[1], gbb[2],
                                     hbb[0], hbb[1], hbb[2], out);
}